// Round 4
// baseline (6258.235 us; speedup 1.0000x reference)
//
#include <hip/hip_runtime.h>
#include <math.h>

typedef _Float16 f16;
typedef _Float16 f16x8 __attribute__((ext_vector_type(8)));
typedef _Float16 f16x4 __attribute__((ext_vector_type(4)));
typedef float floatx4 __attribute__((ext_vector_type(4)));

#define BATCH 256
#define SEQ 64
#define DMODEL 1024
#define NHEAD 16
#define HDIM 64
#define VOCAB 64
#define DFF 4096
#define NLAYER 8
#define MS (BATCH*SEQ)   // 16384 rows

#define GPTR(p) ((const __attribute__((address_space(1))) void*)(p))
#define LPTR(p) ((__attribute__((address_space(3))) void*)(p))

__device__ __forceinline__ floatx4 mfma16(f16x8 a, f16x8 b, floatx4 c) {
    return __builtin_amdgcn_mfma_f32_16x16x32_f16(a, b, c, 0, 0, 0);
}

__device__ __forceinline__ float gelu_f(float x) {
    return 0.5f * x * (1.f + erff(x * 0.70710678118654752f));
}

// ---------------- embed ------------------------------------------------------
__global__ __launch_bounds__(256) void embed_k(const int* __restrict__ x, const int* __restrict__ step,
                                               const float* __restrict__ tok, const float* __restrict__ se,
                                               float* __restrict__ h, f16* __restrict__ hb) {
    int row = blockIdx.x;
    int t = threadIdx.x;
    int id = x[row];
    int si = min(max(step[0], 0), 63);
    float4 a = ((const float4*)(tok + (size_t)id * DMODEL))[t];
    float4 b = ((const float4*)(se + (size_t)si * DMODEL))[t];
    float4 o;
    o.x = a.x + b.x; o.y = a.y + b.y; o.z = a.z + b.z; o.w = a.w + b.w;
    ((float4*)(h + (size_t)row * DMODEL))[t] = o;
    f16x4 hv; hv[0] = (f16)o.x; hv[1] = (f16)o.y; hv[2] = (f16)o.z; hv[3] = (f16)o.w;
    ((f16x4*)(hb + (size_t)row * DMODEL))[t] = hv;
}

// ---------------- fp32 -> f16 convert ----------------------------------------
__global__ __launch_bounds__(256) void cvt_k(const float* __restrict__ src, f16* __restrict__ dst, int n4) {
    int i = blockIdx.x * 256 + threadIdx.x;
    if (i < n4) {
        float4 v = ((const float4*)src)[i];
        f16x4 o; o[0] = (f16)v.x; o[1] = (f16)v.y; o[2] = (f16)v.z; o[3] = (f16)v.w;
        ((f16x4*)dst)[i] = o;
    }
}

// ---------------- GEMM: C[M,N] = A[M,K] @ Bw[N,K]^T --------------------------
// 256x256 tile, BK=64, 2x64KB double-buffer, 8-phase schedule, counted vmcnt(6),
// XOR-swizzled LDS (16B-block ^= row&7) with pre-swizzled global source.
// 8 waves (2M x 4N), per-wave 128x64 output (acc[8][4]).
// MODE 0: store f16 (bias)  MODE 1: store f16 (bias+gelu)  MODE 2: h += acc+bias (fp32)
template<int MODE>
__global__ __launch_bounds__(512, 2) void gemm_k(const f16* __restrict__ A, const f16* __restrict__ Bw,
                                                 const float* __restrict__ bias,
                                                 f16* __restrict__ Cb, float* __restrict__ Hacc,
                                                 int M, int N, int K) {
    __shared__ f16 smem[65536];   // 2 bufs x (A 256x64 + B 256x64) f16 = 128 KB

    const int tid = threadIdx.x;
    const int lane = tid & 63;
    const int wave = tid >> 6;
    const int wm = wave >> 2, wn = wave & 3;     // 2 x 4 wave grid
    const int lr = lane & 15, lg = lane >> 4;
    const int sa = lr & 7;

    // bijective XCD-aware block swizzle (all grids have nwg % 8 == 0)
    const unsigned nx = gridDim.x;
    const unsigned nwg = nx * gridDim.y;
    unsigned flat = blockIdx.y * nx + blockIdx.x;
    flat = (flat & 7u) * (nwg >> 3) + (flat >> 3);
    const int m0 = (int)(flat / nx) * 256;
    const int n0 = (int)(flat % nx) * 256;

    floatx4 acc[8][4] = {};

    // staging: thread t covers (row = c*64 + (t>>3), 16B-block = t&7) of each half-tile.
    // physical block (t&7) holds logical block (t&7)^(row&7) -> pre-swizzled source.
    const int srow = tid >> 3;          // 0..63
    const int scbs = (tid & 7) ^ (srow & 7);
    const f16* Asrc = A + (size_t)(m0 + srow) * K + scbs * 8;
    const f16* Bsrc = Bw + (size_t)(n0 + srow) * K + scbs * 8;
    const int ldsw = wave * 512;        // wave-uniform LDS base (HW adds lane*16B)

    // half-tile q: 0=A rows0-127, 1=A rows128-255, 2=B rows0-127, 3=B rows128-255
#define STAGEH(tt, q) do {                                                                   \
    const f16* _s = (((q) & 2) ? Bsrc : Asrc) + (((q) & 1) ? 128 * (size_t)K : 0)            \
                    + (size_t)(tt) * 64;                                                     \
    const int _lb = (((tt) & 1) << 15) + (((q) & 2) << 13) + (((q) & 1) << 13) + ldsw;       \
    __builtin_amdgcn_global_load_lds(GPTR(_s),                  LPTR(smem + _lb),        16, 0, 0); \
    __builtin_amdgcn_global_load_lds(GPTR(_s + 64 * (size_t)K), LPTR(smem + _lb + 4096), 16, 0, 0); \
} while (0)

#define LOADA(mb, kh) do {                                                                   \
    const f16* _p = smem + pofs + (wm * 128 + (mb) * 64 + lr) * 64                           \
                    + ((((kh) * 4 + lg) ^ sa) << 3);                                         \
    af[0] = *(const f16x8*)(_p);                                                             \
    af[1] = *(const f16x8*)(_p + 1024);                                                      \
    af[2] = *(const f16x8*)(_p + 2048);                                                      \
    af[3] = *(const f16x8*)(_p + 3072);                                                      \
} while (0)

#define LOADB(kh) do {                                                                       \
    const f16* _p = smem + pofs + 16384 + (wn * 64 + lr) * 64                                \
                    + ((((kh) * 4 + lg) ^ sa) << 3);                                         \
    bf[0] = *(const f16x8*)(_p);                                                             \
    bf[1] = *(const f16x8*)(_p + 1024);                                                      \
    bf[2] = *(const f16x8*)(_p + 2048);                                                      \
    bf[3] = *(const f16x8*)(_p + 3072);                                                      \
} while (0)

#define MFMA_BLK(mb) do {                                                                    \
    _Pragma("unroll") for (int i = 0; i < 4; ++i)                                            \
    _Pragma("unroll") for (int ni = 0; ni < 4; ++ni)                                         \
        acc[(mb) * 4 + i][ni] = mfma16(af[i], bf[ni], acc[(mb) * 4 + i][ni]);                \
} while (0)

#define BARR() __builtin_amdgcn_s_barrier()
#define VMW(n) asm volatile("s_waitcnt vmcnt(" #n ")" ::: "memory")
#define LGKM0() asm volatile("s_waitcnt lgkmcnt(0)" ::: "memory")
#define PRIO(x) __builtin_amdgcn_s_setprio(x)

    const int NT = K >> 6;   // K-tiles (K >= 1024 -> NT >= 16)

    // prologue: tile0 fully + 3 half-tiles of tile1 in flight
    STAGEH(0, 0); STAGEH(0, 1); STAGEH(0, 2); STAGEH(0, 3);
    STAGEH(1, 0); STAGEH(1, 1); STAGEH(1, 2);
    VMW(6);
    BARR();

    for (int t = 0; t < NT; ++t) {
        const int pofs = (t & 1) << 15;
        f16x8 af[4], bf[4];
        // phase 0: quadrant (mb=0, kh=0)
        LOADB(0); LOADA(0, 0);
        BARR(); LGKM0();
        PRIO(1); MFMA_BLK(0); PRIO(0);
        BARR();
        // phase 1: quadrant (mb=1, kh=0) + stage last half-tile of t+1
        LOADA(1, 0);
        if (t + 1 < NT) STAGEH(t + 1, 3);
        BARR(); LGKM0();
        PRIO(1); MFMA_BLK(1); PRIO(0);
        BARR();
        // phase 2: quadrant (mb=0, kh=1)
        LOADB(1); LOADA(0, 1);
        BARR(); LGKM0();
        PRIO(1); MFMA_BLK(0); PRIO(0);
        BARR();
        // phase 3: quadrant (mb=1, kh=1)
        LOADA(1, 1);
        BARR(); LGKM0();
        PRIO(1); MFMA_BLK(1); PRIO(0);
        BARR();
        // boundary: issue 3 half-tiles of t+2 (buffer t&1, all reads done), then
        // counted wait ensures tile t+1 complete with 6 loads still in flight.
        if (t + 2 < NT) {
            STAGEH(t + 2, 0); STAGEH(t + 2, 1); STAGEH(t + 2, 2);
            VMW(6);
            BARR();
        } else if (t + 1 < NT) {
            VMW(0);
            BARR();
        }
    }
#undef STAGEH
#undef LOADA
#undef LOADB
#undef MFMA_BLK

    if (MODE == 2) {
#pragma unroll
        for (int ni = 0; ni < 4; ++ni) {
            int cc = n0 + wn * 64 + ni * 16 + lr;
            float bvl = bias[cc];
#pragma unroll
            for (int mi = 0; mi < 8; ++mi)
#pragma unroll
                for (int j = 0; j < 4; ++j) {
                    int rr = m0 + wm * 128 + mi * 16 + lg * 4 + j;
                    float* p = Hacc + (size_t)rr * N + cc;
                    *p += acc[mi][ni][j] + bvl;
                }
        }
    } else {
        __syncthreads();                       // full drain; smem reused as scratch
        float bsv[4];
#pragma unroll
        for (int ni = 0; ni < 4; ++ni) bsv[ni] = bias[n0 + wn * 64 + ni * 16 + lr];
        f16* scr = smem + wave * 4096;         // wave-private 64x64 f16, XOR-swizzled blocks
#pragma unroll
        for (int half = 0; half < 2; ++half) {
#pragma unroll
            for (int mi = 0; mi < 4; ++mi)
#pragma unroll
                for (int ni = 0; ni < 4; ++ni)
#pragma unroll
                    for (int j = 0; j < 4; ++j) {
                        int r = mi * 16 + lg * 4 + j;
                        int c = ni * 16 + lr;
                        float v = acc[half * 4 + mi][ni][j] + bsv[ni];
                        if (MODE == 1) v = gelu_f(v);
                        scr[r * 64 + (((c >> 3) ^ (r & 7)) * 8) + (c & 7)] = (f16)v;
                    }
            __syncthreads();
            int gr = m0 + wm * 128 + half * 64 + lane;
            f16* dst = Cb + (size_t)gr * N + n0 + wn * 64;
#pragma unroll
            for (int i = 0; i < 8; ++i) {
                f16x8 v = *(const f16x8*)(scr + lane * 64 + ((i ^ (lane & 7)) * 8));
                *(f16x8*)(dst + i * 8) = v;
            }
            __syncthreads();
        }
    }
}

// ---------------- attention: one wave per (b,h) -------------------------------
__global__ __launch_bounds__(64) void attn_k(const f16* __restrict__ qkv, const float* __restrict__ rb,
                                             f16* __restrict__ ctx) {
    const int hh = blockIdx.x;
    const int bb = blockIdx.y;
    const int lane = threadIdx.x;
    __shared__ float rbs[128];
    __shared__ f16 Vt[64][72];
    __shared__ f16 Pl[64][72];

    for (int i = lane; i < 127; i += 64) rbs[i] = rb[i];

    const f16* vrow = qkv + (size_t)(bb * 64 + lane) * 3072 + 2048 + hh * 64;
#pragma unroll
    for (int i = 0; i < 8; ++i) {
        f16x8 v = *(const f16x8*)(vrow + i * 8);
#pragma unroll
        for (int j = 0; j < 8; ++j) Vt[i * 8 + j][lane] = v[j];
    }
    __syncthreads();

    const int lr = lane & 15, lg = lane >> 4;
    floatx4 sacc[4][4] = {};
    const f16* qbase = qkv + (size_t)(bb * 64) * 3072 + hh * 64;
#pragma unroll
    for (int kk = 0; kk < 64; kk += 32) {
        f16x8 qa[4], kb[4];
#pragma unroll
        for (int mf = 0; mf < 4; ++mf)
            qa[mf] = *(const f16x8*)(qbase + (size_t)(mf * 16 + lr) * 3072 + kk + lg * 8);
#pragma unroll
        for (int nf = 0; nf < 4; ++nf)
            kb[nf] = *(const f16x8*)(qbase + 1024 + (size_t)(nf * 16 + lr) * 3072 + kk + lg * 8);
#pragma unroll
        for (int mf = 0; mf < 4; ++mf)
#pragma unroll
            for (int nf = 0; nf < 4; ++nf)
                sacc[mf][nf] = mfma16(qa[mf], kb[nf], sacc[mf][nf]);
    }

#pragma unroll
    for (int mf = 0; mf < 4; ++mf) {
#pragma unroll
        for (int j = 0; j < 4; ++j) {
            int qrow = mf * 16 + lg * 4 + j;
            float v0 = sacc[mf][0][j] * 0.125f + rbs[qrow - (0  + lr) + 63];
            float v1 = sacc[mf][1][j] * 0.125f + rbs[qrow - (16 + lr) + 63];
            float v2 = sacc[mf][2][j] * 0.125f + rbs[qrow - (32 + lr) + 63];
            float v3 = sacc[mf][3][j] * 0.125f + rbs[qrow - (48 + lr) + 63];
            float mx = fmaxf(fmaxf(v0, v1), fmaxf(v2, v3));
            for (int m = 1; m < 16; m <<= 1) mx = fmaxf(mx, __shfl_xor(mx, m));
            v0 = __expf(v0 - mx); v1 = __expf(v1 - mx); v2 = __expf(v2 - mx); v3 = __expf(v3 - mx);
            float sum = v0 + v1 + v2 + v3;
            for (int m = 1; m < 16; m <<= 1) sum += __shfl_xor(sum, m);
            float inv = 1.f / sum;
            Pl[qrow][0  + lr] = (f16)(v0 * inv);
            Pl[qrow][16 + lr] = (f16)(v1 * inv);
            Pl[qrow][32 + lr] = (f16)(v2 * inv);
            Pl[qrow][48 + lr] = (f16)(v3 * inv);
        }
    }
    __syncthreads();

    floatx4 oacc[4][4] = {};
#pragma unroll
    for (int kk = 0; kk < 64; kk += 32) {
        f16x8 pa[4], vb[4];
#pragma unroll
        for (int mf = 0; mf < 4; ++mf) pa[mf] = *(const f16x8*)&Pl[mf * 16 + lr][kk + lg * 8];
#pragma unroll
        for (int nf = 0; nf < 4; ++nf) vb[nf] = *(const f16x8*)&Vt[nf * 16 + lr][kk + lg * 8];
#pragma unroll
        for (int mf = 0; mf < 4; ++mf)
#pragma unroll
            for (int nf = 0; nf < 4; ++nf)
                oacc[mf][nf] = mfma16(pa[mf], vb[nf], oacc[mf][nf]);
    }
    __syncthreads();
#pragma unroll
    for (int mf = 0; mf < 4; ++mf)
#pragma unroll
        for (int nf = 0; nf < 4; ++nf)
#pragma unroll
            for (int j = 0; j < 4; ++j)
                Pl[mf * 16 + lg * 4 + j][nf * 16 + lr] = (f16)oacc[mf][nf][j];
    __syncthreads();
    f16* crow = ctx + (size_t)(bb * 64 + lane) * DMODEL + hh * 64;
#pragma unroll
    for (int i = 0; i < 8; ++i) {
        f16x8 v = *(const f16x8*)&Pl[lane][i * 8];
        *(f16x8*)(crow + i * 8) = v;
    }
}

// ---------------- LayerNorm in-place on h, optionally emit f16 copy -----------
__global__ __launch_bounds__(256) void ln_k(float* __restrict__ h, const float* __restrict__ g,
                                            const float* __restrict__ b, f16* __restrict__ hb, int emit) {
    int row = blockIdx.x;
    int t = threadIdx.x;
    float4 v = ((const float4*)(h + (size_t)row * DMODEL))[t];
    float s = v.x + v.y + v.z + v.w;
    float ss = v.x * v.x + v.y * v.y + v.z * v.z + v.w * v.w;
    for (int m = 1; m < 64; m <<= 1) { s += __shfl_xor(s, m); ss += __shfl_xor(ss, m); }
    __shared__ float red[8];
    if ((t & 63) == 0) { red[(t >> 6) * 2] = s; red[(t >> 6) * 2 + 1] = ss; }
    __syncthreads();
    s = red[0] + red[2] + red[4] + red[6];
    ss = red[1] + red[3] + red[5] + red[7];
    float mean = s * (1.f / 1024.f);
    float var = ss * (1.f / 1024.f) - mean * mean;
    float rstd = rsqrtf(var + 1e-5f);
    float4 gg = ((const float4*)g)[t];
    float4 bb = ((const float4*)b)[t];
    float4 o;
    o.x = (v.x - mean) * rstd * gg.x + bb.x;
    o.y = (v.y - mean) * rstd * gg.y + bb.y;
    o.z = (v.z - mean) * rstd * gg.z + bb.z;
    o.w = (v.w - mean) * rstd * gg.w + bb.w;
    ((float4*)(h + (size_t)row * DMODEL))[t] = o;
    if (emit) {
        f16x4 hv; hv[0] = (f16)o.x; hv[1] = (f16)o.y; hv[2] = (f16)o.z; hv[3] = (f16)o.w;
        ((f16x4*)(hb + (size_t)row * DMODEL))[t] = hv;
    }
}

// ---------------- mean over S -------------------------------------------------
__global__ __launch_bounds__(256) void pool_k(const float* __restrict__ h, float* __restrict__ pooled) {
    int b = blockIdx.x;
    int t = threadIdx.x;
    float sx = 0, sy = 0, sz = 0, sw = 0;
    for (int s = 0; s < SEQ; ++s) {
        float4 v = ((const float4*)(h + (size_t)(b * SEQ + s) * DMODEL))[t];
        sx += v.x; sy += v.y; sz += v.z; sw += v.w;
    }
    float4 o; o.x = sx * (1.f / 64.f); o.y = sy * (1.f / 64.f); o.z = sz * (1.f / 64.f); o.w = sw * (1.f / 64.f);
    ((float4*)(pooled + (size_t)b * DMODEL))[t] = o;
}

// ---------------- policy / value heads ---------------------------------------
__global__ __launch_bounds__(64) void head_k(const float* __restrict__ pooled, const float* __restrict__ pw,
                                             const float* __restrict__ pb, const float* __restrict__ vw,
                                             const float* __restrict__ vb, float* __restrict__ out) {
    int b = blockIdx.x;
    int lane = threadIdx.x;
    const float* pr = pooled + (size_t)b * DMODEL;
    const float* wr = pw + (size_t)lane * DMODEL;
    float accp = 0.f;
    for (int d = 0; d < DMODEL; d += 4) {
        float4 x = *(const float4*)(pr + d);
        float4 w = *(const float4*)(wr + d);
        accp += x.x * w.x + x.y * w.y + x.z * w.z + x.w * w.w;
    }
    float accv = 0.f;
    for (int d = lane * 4; d < DMODEL; d += 256) {
        float4 x = *(const float4*)(pr + d);
        float4 w = *(const float4*)(vw + d);
        accv += x.x * w.x + x.y * w.y + x.z * w.z + x.w * w.w;
    }
    for (int m = 1; m < 64; m <<= 1) accv += __shfl_xor(accv, m);
    out[b * VOCAB + lane] = accp + pb[lane];
    if (lane == 0) out[BATCH * VOCAB + b] = accv + vb[0];
}

extern "C" void kernel_launch(void* const* d_in, const int* in_sizes, int n_in,
                              void* d_out, int out_size, void* d_ws, size_t ws_size,
                              hipStream_t stream) {
    const int*   x      = (const int*)d_in[0];
    const int*   step   = (const int*)d_in[1];
    const float* tok    = (const float*)d_in[2];
    const float* se     = (const float*)d_in[3];
    const float* qkv_w  = (const float*)d_in[4];
    const float* qkv_b  = (const float*)d_in[5];
    const float* out_w  = (const float*)d_in[6];
    const float* out_b  = (const float*)d_in[7];
    const float* relb   = (const float*)d_in[8];
    const float* w1     = (const float*)d_in[9];
    const float* b1     = (const float*)d_in[10];
    const float* w2     = (const float*)d_in[11];
    const float* b2     = (const float*)d_in[12];
    const float* ln1g   = (const float*)d_in[13];
    const float* ln1b   = (const float*)d_in[14];
    const float* ln2g   = (const float*)d_in[15];
    const float* ln2b   = (const float*)d_in[16];
    const float* lnog   = (const float*)d_in[17];
    const float* lnob   = (const float*)d_in[18];
    const float* pw     = (const float*)d_in[19];
    const float* pb     = (const float*)d_in[20];
    const float* vw     = (const float*)d_in[21];
    const float* vb     = (const float*)d_in[22];

    float* out = (float*)d_out;
    float* h = out + BATCH * VOCAB + BATCH;       // h region: [16384,1024] fp32

    char* ws = (char*)d_ws;
    f16* hb     = (f16*)(ws);                                  // 33,554,432 B
    f16* uni    = (f16*)(ws + 33554432);                       // qkv16 / ffn16 union
    f16* qkv16  = uni;
    f16* ffn16  = uni;
    f16* ctx16  = (f16*)(ws + 167772160);
    f16* wqb    = (f16*)(ws + 201326592);
    f16* wob    = (f16*)(ws + 207618048);
    f16* w1b    = (f16*)(ws + 209715200);
    f16* w2b    = (f16*)(ws + 218103808);
    float* pooled = (float*)(ws + 226492416);

    embed_k<<<MS, 256, 0, stream>>>(x, step, tok, se, h, hb);

    for (int l = 0; l < NLAYER; ++l) {
        cvt_k<<<3072, 256, 0, stream>>>(qkv_w + (size_t)l * 3145728, wqb, 786432);
        cvt_k<<<1024, 256, 0, stream>>>(out_w + (size_t)l * 1048576, wob, 262144);
        cvt_k<<<4096, 256, 0, stream>>>(w1 + (size_t)l * 4194304, w1b, 1048576);
        cvt_k<<<4096, 256, 0, stream>>>(w2 + (size_t)l * 4194304, w2b, 1048576);

        gemm_k<0><<<dim3(12, 64), 512, 0, stream>>>(hb, wqb, qkv_b + l * 3072, qkv16, nullptr, MS, 3072, 1024);
        attn_k<<<dim3(NHEAD, BATCH), 64, 0, stream>>>(qkv16, relb + l * 127, ctx16);
        gemm_k<2><<<dim3(4, 64), 512, 0, stream>>>(ctx16, wob, out_b + l * 1024, nullptr, h, MS, 1024, 1024);
        ln_k<<<MS, 256, 0, stream>>>(h, ln1g + l * 1024, ln1b + l * 1024, hb, 1);
        gemm_k<1><<<dim3(16, 64), 512, 0, stream>>>(hb, w1b, b1 + l * 4096, ffn16, nullptr, MS, 4096, 1024);
        gemm_k<2><<<dim3(4, 64), 512, 0, stream>>>(ffn16, w2b, b2 + l * 1024, nullptr, h, MS, 1024, 4096);
        ln_k<<<MS, 256, 0, stream>>>(h, ln2g + l * 1024, ln2b + l * 1024, hb, 1);
    }

    ln_k<<<MS, 256, 0, stream>>>(h, lnog, lnob, hb, 0);
    pool_k<<<BATCH, 256, 0, stream>>>(h, pooled);
    head_k<<<BATCH, 64, 0, stream>>>(pooled, pw, pb, vw, vb, out);
}

// Round 5
// 5905.252 us; speedup vs baseline: 1.0598x; 1.0598x over previous
//
#include <hip/hip_runtime.h>
#include <math.h>

typedef _Float16 f16;
typedef _Float16 f16x8 __attribute__((ext_vector_type(8)));
typedef _Float16 f16x4 __attribute__((ext_vector_type(4)));
typedef float floatx4 __attribute__((ext_vector_type(4)));

#define BATCH 256
#define SEQ 64
#define DMODEL 1024
#define NHEAD 16
#define HDIM 64
#define VOCAB 64
#define DFF 4096
#define NLAYER 8
#define MS (BATCH*SEQ)   // 16384 rows

#define GPTR(p) ((const __attribute__((address_space(1))) void*)(p))
#define LPTR(p) ((__attribute__((address_space(3))) void*)(p))

__device__ __forceinline__ floatx4 mfma16(f16x8 a, f16x8 b, floatx4 c) {
    return __builtin_amdgcn_mfma_f32_16x16x32_f16(a, b, c, 0, 0, 0);
}

__device__ __forceinline__ float gelu_f(float x) {
    return 0.5f * x * (1.f + erff(x * 0.70710678118654752f));
}

// ---------------- embed ------------------------------------------------------
__global__ __launch_bounds__(256) void embed_k(const int* __restrict__ x, const int* __restrict__ step,
                                               const float* __restrict__ tok, const float* __restrict__ se,
                                               float* __restrict__ h, f16* __restrict__ hb) {
    int row = blockIdx.x;
    int t = threadIdx.x;
    int id = x[row];
    int si = min(max(step[0], 0), 63);
    float4 a = ((const float4*)(tok + (size_t)id * DMODEL))[t];
    float4 b = ((const float4*)(se + (size_t)si * DMODEL))[t];
    float4 o;
    o.x = a.x + b.x; o.y = a.y + b.y; o.z = a.z + b.z; o.w = a.w + b.w;
    ((float4*)(h + (size_t)row * DMODEL))[t] = o;
    f16x4 hv; hv[0] = (f16)o.x; hv[1] = (f16)o.y; hv[2] = (f16)o.z; hv[3] = (f16)o.w;
    ((f16x4*)(hb + (size_t)row * DMODEL))[t] = hv;
}

// ---------------- fp32 -> f16 convert ----------------------------------------
__global__ __launch_bounds__(256) void cvt_k(const float* __restrict__ src, f16* __restrict__ dst, int n4) {
    int i = blockIdx.x * 256 + threadIdx.x;
    if (i < n4) {
        float4 v = ((const float4*)src)[i];
        f16x4 o; o[0] = (f16)v.x; o[1] = (f16)v.y; o[2] = (f16)v.z; o[3] = (f16)v.w;
        ((f16x4*)dst)[i] = o;
    }
}

// ---------------- GEMM: C[M,N] = A[M,K] @ Bw[N,K]^T --------------------------
// 256x256 tile, BK=64, 2x64KB double-buffer. Counted-vmcnt pipeline:
// per K-tile: [vmcnt(8); barrier] ds_read B+A0 -> MFMA mb0 (A1 reads overlap)
//             [lgkm0; barrier] STAGE(t+2) -> MFMA mb1.  2 barriers/tile.
// T2 XOR swizzle: physical 16B-block b holds logical b^(row&7) (pre-swizzled src).
// 8 waves (2M x 4N), per-wave 128x64 output (acc[8][4]).
// MODE 0: store f16 (bias)  MODE 1: store f16 (bias+gelu)  MODE 2: h += acc+bias (fp32)
template<int MODE>
__global__ __launch_bounds__(512, 2) void gemm_k(const f16* __restrict__ A, const f16* __restrict__ Bw,
                                                 const float* __restrict__ bias,
                                                 f16* __restrict__ Cb, float* __restrict__ Hacc,
                                                 int M, int N, int K) {
    __shared__ f16 smem[65536];   // 2 bufs x (A 256x64 + B 256x64) f16 = 128 KB

    const int tid = threadIdx.x;
    const int lane = tid & 63;
    const int wave = tid >> 6;
    const int wm = wave >> 2, wn = wave & 3;     // 2 x 4 wave grid
    const int lr = lane & 15, lg = lane >> 4;
    const int sa = lr & 7;

    // bijective XCD-aware block swizzle (all grids have nwg % 8 == 0)
    const unsigned nx = gridDim.x;
    const unsigned nwg = nx * gridDim.y;
    unsigned flat = blockIdx.y * nx + blockIdx.x;
    flat = (flat & 7u) * (nwg >> 3) + (flat >> 3);
    const int m0 = (int)(flat / nx) * 256;
    const int n0 = (int)(flat % nx) * 256;

    floatx4 acc[8][4] = {};

    // staging: thread t covers (row = 64c + (t>>3), 16B-block = t&7); pre-swizzled source.
    const int srow = tid >> 3;          // 0..63
    const int scbs = (tid & 7) ^ (srow & 7);
    const f16* Asrc = A + (size_t)(m0 + srow) * K + scbs * 8;
    const f16* Bsrc = Bw + (size_t)(n0 + srow) * K + scbs * 8;
    const int ldsw = wave * 512;        // wave-uniform LDS base (HW adds lane*16B)

#define STAGE(bi, tt) do {                                                                        \
    const f16* _a = Asrc + (size_t)(tt) * 64;                                                     \
    const f16* _b = Bsrc + (size_t)(tt) * 64;                                                     \
    f16* _l = smem + ((bi) << 15) + ldsw;                                                         \
    __builtin_amdgcn_global_load_lds(GPTR(_a),                   LPTR(_l),         16, 0, 0);     \
    __builtin_amdgcn_global_load_lds(GPTR(_a +  64 * (size_t)K), LPTR(_l + 4096),  16, 0, 0);     \
    __builtin_amdgcn_global_load_lds(GPTR(_a + 128 * (size_t)K), LPTR(_l + 8192),  16, 0, 0);     \
    __builtin_amdgcn_global_load_lds(GPTR(_a + 192 * (size_t)K), LPTR(_l + 12288), 16, 0, 0);     \
    __builtin_amdgcn_global_load_lds(GPTR(_b),                   LPTR(_l + 16384), 16, 0, 0);     \
    __builtin_amdgcn_global_load_lds(GPTR(_b +  64 * (size_t)K), LPTR(_l + 20480), 16, 0, 0);     \
    __builtin_amdgcn_global_load_lds(GPTR(_b + 128 * (size_t)K), LPTR(_l + 24576), 16, 0, 0);     \
    __builtin_amdgcn_global_load_lds(GPTR(_b + 192 * (size_t)K), LPTR(_l + 28672), 16, 0, 0);     \
} while (0)

    const int NT = K >> 6;   // K >= 128 always here

    STAGE(0, 0);
    STAGE(1, 1);

    for (int t = 0; t < NT; ++t) {
        // buffer-ready: tile t's 8 loads are the oldest; t+1's 8 stay in flight.
        if (t + 1 < NT) { asm volatile("s_waitcnt vmcnt(8)" ::: "memory"); }
        else            { asm volatile("s_waitcnt vmcnt(0)" ::: "memory"); }
        __builtin_amdgcn_s_barrier();

        const f16* Ab = smem + ((t & 1) << 15);
        const f16* Bb = Ab + 16384;
        f16x8 bf[8], af[8], ag[8];
#pragma unroll
        for (int kh = 0; kh < 2; ++kh)
#pragma unroll
            for (int ni = 0; ni < 4; ++ni)
                bf[kh * 4 + ni] = *(const f16x8*)(Bb + (wn * 64 + ni * 16 + lr) * 64
                                                  + (((kh * 4 + lg) ^ sa) << 3));
#pragma unroll
        for (int kh = 0; kh < 2; ++kh)
#pragma unroll
            for (int mi = 0; mi < 4; ++mi)
                af[kh * 4 + mi] = *(const f16x8*)(Ab + (wm * 128 + mi * 16 + lr) * 64
                                                  + (((kh * 4 + lg) ^ sa) << 3));

        __builtin_amdgcn_s_setprio(1);
#pragma unroll
        for (int kh = 0; kh < 2; ++kh)
#pragma unroll
            for (int mi = 0; mi < 4; ++mi)
#pragma unroll
                for (int ni = 0; ni < 4; ++ni)
                    acc[mi][ni] = mfma16(af[kh * 4 + mi], bf[kh * 4 + ni], acc[mi][ni]);
        __builtin_amdgcn_s_setprio(0);

#pragma unroll
        for (int kh = 0; kh < 2; ++kh)
#pragma unroll
            for (int mi = 0; mi < 4; ++mi)
                ag[kh * 4 + mi] = *(const f16x8*)(Ab + (wm * 128 + 64 + mi * 16 + lr) * 64
                                                  + (((kh * 4 + lg) ^ sa) << 3));
        // WAR fence: every wave has all its reads of this buffer in regs.
        asm volatile("s_waitcnt lgkmcnt(0)" ::: "memory");
        __builtin_amdgcn_s_barrier();

        if (t + 2 < NT) STAGE(t & 1, t + 2);   // overwrite just-consumed buffer

        __builtin_amdgcn_s_setprio(1);
#pragma unroll
        for (int kh = 0; kh < 2; ++kh)
#pragma unroll
            for (int mi = 0; mi < 4; ++mi)
#pragma unroll
                for (int ni = 0; ni < 4; ++ni)
                    acc[4 + mi][ni] = mfma16(ag[kh * 4 + mi], bf[kh * 4 + ni], acc[4 + mi][ni]);
        __builtin_amdgcn_s_setprio(0);
    }
#undef STAGE

    if (MODE == 2) {
#pragma unroll
        for (int ni = 0; ni < 4; ++ni) {
            int cc = n0 + wn * 64 + ni * 16 + lr;
            float bvl = bias[cc];
#pragma unroll
            for (int mi = 0; mi < 8; ++mi)
#pragma unroll
                for (int j = 0; j < 4; ++j) {
                    int rr = m0 + wm * 128 + mi * 16 + lg * 4 + j;
                    float* p = Hacc + (size_t)rr * N + cc;
                    *p += acc[mi][ni][j] + bvl;
                }
        }
    } else {
        // NT is even for all our K -> final tile read buf1; buf0 free as scratch.
        float bsv[4];
#pragma unroll
        for (int ni = 0; ni < 4; ++ni) bsv[ni] = bias[n0 + wn * 64 + ni * 16 + lr];
        f16* scr = smem + wave * 4096;         // wave-private 64x64 f16, XOR-swizzled blocks
#pragma unroll
        for (int half = 0; half < 2; ++half) {
#pragma unroll
            for (int mi = 0; mi < 4; ++mi)
#pragma unroll
                for (int ni = 0; ni < 4; ++ni)
#pragma unroll
                    for (int j = 0; j < 4; ++j) {
                        int r = mi * 16 + lg * 4 + j;
                        int c = ni * 16 + lr;
                        float v = acc[half * 4 + mi][ni][j] + bsv[ni];
                        if (MODE == 1) v = gelu_f(v);
                        scr[r * 64 + (((c >> 3) ^ (r & 7)) * 8) + (c & 7)] = (f16)v;
                    }
            int gr = m0 + wm * 128 + half * 64 + lane;
            f16* dst = Cb + (size_t)gr * N + n0 + wn * 64;
#pragma unroll
            for (int i = 0; i < 8; ++i) {
                f16x8 v = *(const f16x8*)(scr + lane * 64 + ((i ^ (lane & 7)) * 8));
                *(f16x8*)(dst + i * 8) = v;
            }
        }
    }
}

// ---------------- attention: one wave per (b,h) -------------------------------
__global__ __launch_bounds__(64) void attn_k(const f16* __restrict__ qkv, const float* __restrict__ rb,
                                             f16* __restrict__ ctx) {
    const int hh = blockIdx.x;
    const int bb = blockIdx.y;
    const int lane = threadIdx.x;
    __shared__ float rbs[128];
    __shared__ f16 Vt[64][72];
    __shared__ f16 Pl[64][72];

    for (int i = lane; i < 127; i += 64) rbs[i] = rb[i];

    const f16* vrow = qkv + (size_t)(bb * 64 + lane) * 3072 + 2048 + hh * 64;
#pragma unroll
    for (int i = 0; i < 8; ++i) {
        f16x8 v = *(const f16x8*)(vrow + i * 8);
#pragma unroll
        for (int j = 0; j < 8; ++j) Vt[i * 8 + j][lane] = v[j];
    }
    __syncthreads();

    const int lr = lane & 15, lg = lane >> 4;
    floatx4 sacc[4][4] = {};
    const f16* qbase = qkv + (size_t)(bb * 64) * 3072 + hh * 64;
#pragma unroll
    for (int kk = 0; kk < 64; kk += 32) {
        f16x8 qa[4], kb[4];
#pragma unroll
        for (int mf = 0; mf < 4; ++mf)
            qa[mf] = *(const f16x8*)(qbase + (size_t)(mf * 16 + lr) * 3072 + kk + lg * 8);
#pragma unroll
        for (int nf = 0; nf < 4; ++nf)
            kb[nf] = *(const f16x8*)(qbase + 1024 + (size_t)(nf * 16 + lr) * 3072 + kk + lg * 8);
#pragma unroll
        for (int mf = 0; mf < 4; ++mf)
#pragma unroll
            for (int nf = 0; nf < 4; ++nf)
                sacc[mf][nf] = mfma16(qa[mf], kb[nf], sacc[mf][nf]);
    }

#pragma unroll
    for (int mf = 0; mf < 4; ++mf) {
#pragma unroll
        for (int j = 0; j < 4; ++j) {
            int qrow = mf * 16 + lg * 4 + j;
            float v0 = sacc[mf][0][j] * 0.125f + rbs[qrow - (0  + lr) + 63];
            float v1 = sacc[mf][1][j] * 0.125f + rbs[qrow - (16 + lr) + 63];
            float v2 = sacc[mf][2][j] * 0.125f + rbs[qrow - (32 + lr) + 63];
            float v3 = sacc[mf][3][j] * 0.125f + rbs[qrow - (48 + lr) + 63];
            float mx = fmaxf(fmaxf(v0, v1), fmaxf(v2, v3));
            for (int m = 1; m < 16; m <<= 1) mx = fmaxf(mx, __shfl_xor(mx, m));
            v0 = __expf(v0 - mx); v1 = __expf(v1 - mx); v2 = __expf(v2 - mx); v3 = __expf(v3 - mx);
            float sum = v0 + v1 + v2 + v3;
            for (int m = 1; m < 16; m <<= 1) sum += __shfl_xor(sum, m);
            float inv = 1.f / sum;
            Pl[qrow][0  + lr] = (f16)(v0 * inv);
            Pl[qrow][16 + lr] = (f16)(v1 * inv);
            Pl[qrow][32 + lr] = (f16)(v2 * inv);
            Pl[qrow][48 + lr] = (f16)(v3 * inv);
        }
    }
    __syncthreads();

    floatx4 oacc[4][4] = {};
#pragma unroll
    for (int kk = 0; kk < 64; kk += 32) {
        f16x8 pa[4], vb[4];
#pragma unroll
        for (int mf = 0; mf < 4; ++mf) pa[mf] = *(const f16x8*)&Pl[mf * 16 + lr][kk + lg * 8];
#pragma unroll
        for (int nf = 0; nf < 4; ++nf) vb[nf] = *(const f16x8*)&Vt[nf * 16 + lr][kk + lg * 8];
#pragma unroll
        for (int mf = 0; mf < 4; ++mf)
#pragma unroll
            for (int nf = 0; nf < 4; ++nf)
                oacc[mf][nf] = mfma16(pa[mf], vb[nf], oacc[mf][nf]);
    }
    __syncthreads();
#pragma unroll
    for (int mf = 0; mf < 4; ++mf)
#pragma unroll
        for (int nf = 0; nf < 4; ++nf)
#pragma unroll
            for (int j = 0; j < 4; ++j)
                Pl[mf * 16 + lg * 4 + j][nf * 16 + lr] = (f16)oacc[mf][nf][j];
    __syncthreads();
    f16* crow = ctx + (size_t)(bb * 64 + lane) * DMODEL + hh * 64;
#pragma unroll
    for (int i = 0; i < 8; ++i) {
        f16x8 v = *(const f16x8*)&Pl[lane][i * 8];
        *(f16x8*)(crow + i * 8) = v;
    }
}

// ---------------- LayerNorm in-place on h, optionally emit f16 copy -----------
__global__ __launch_bounds__(256) void ln_k(float* __restrict__ h, const float* __restrict__ g,
                                            const float* __restrict__ b, f16* __restrict__ hb, int emit) {
    int row = blockIdx.x;
    int t = threadIdx.x;
    float4 v = ((const float4*)(h + (size_t)row * DMODEL))[t];
    float s = v.x + v.y + v.z + v.w;
    float ss = v.x * v.x + v.y * v.y + v.z * v.z + v.w * v.w;
    for (int m = 1; m < 64; m <<= 1) { s += __shfl_xor(s, m); ss += __shfl_xor(ss, m); }
    __shared__ float red[8];
    if ((t & 63) == 0) { red[(t >> 6) * 2] = s; red[(t >> 6) * 2 + 1] = ss; }
    __syncthreads();
    s = red[0] + red[2] + red[4] + red[6];
    ss = red[1] + red[3] + red[5] + red[7];
    float mean = s * (1.f / 1024.f);
    float var = ss * (1.f / 1024.f) - mean * mean;
    float rstd = rsqrtf(var + 1e-5f);
    float4 gg = ((const float4*)g)[t];
    float4 bb = ((const float4*)b)[t];
    float4 o;
    o.x = (v.x - mean) * rstd * gg.x + bb.x;
    o.y = (v.y - mean) * rstd * gg.y + bb.y;
    o.z = (v.z - mean) * rstd * gg.z + bb.z;
    o.w = (v.w - mean) * rstd * gg.w + bb.w;
    ((float4*)(h + (size_t)row * DMODEL))[t] = o;
    if (emit) {
        f16x4 hv; hv[0] = (f16)o.x; hv[1] = (f16)o.y; hv[2] = (f16)o.z; hv[3] = (f16)o.w;
        ((f16x4*)(hb + (size_t)row * DMODEL))[t] = hv;
    }
}

// ---------------- mean over S -------------------------------------------------
__global__ __launch_bounds__(256) void pool_k(const float* __restrict__ h, float* __restrict__ pooled) {
    int b = blockIdx.x;
    int t = threadIdx.x;
    float sx = 0, sy = 0, sz = 0, sw = 0;
    for (int s = 0; s < SEQ; ++s) {
        float4 v = ((const float4*)(h + (size_t)(b * SEQ + s) * DMODEL))[t];
        sx += v.x; sy += v.y; sz += v.z; sw += v.w;
    }
    float4 o; o.x = sx * (1.f / 64.f); o.y = sy * (1.f / 64.f); o.z = sz * (1.f / 64.f); o.w = sw * (1.f / 64.f);
    ((float4*)(pooled + (size_t)b * DMODEL))[t] = o;
}

// ---------------- policy / value heads ---------------------------------------
__global__ __launch_bounds__(64) void head_k(const float* __restrict__ pooled, const float* __restrict__ pw,
                                             const float* __restrict__ pb, const float* __restrict__ vw,
                                             const float* __restrict__ vb, float* __restrict__ out) {
    int b = blockIdx.x;
    int lane = threadIdx.x;
    const float* pr = pooled + (size_t)b * DMODEL;
    const float* wr = pw + (size_t)lane * DMODEL;
    float accp = 0.f;
    for (int d = 0; d < DMODEL; d += 4) {
        float4 x = *(const float4*)(pr + d);
        float4 w = *(const float4*)(wr + d);
        accp += x.x * w.x + x.y * w.y + x.z * w.z + x.w * w.w;
    }
    float accv = 0.f;
    for (int d = lane * 4; d < DMODEL; d += 256) {
        float4 x = *(const float4*)(pr + d);
        float4 w = *(const float4*)(vw + d);
        accv += x.x * w.x + x.y * w.y + x.z * w.z + x.w * w.w;
    }
    for (int m = 1; m < 64; m <<= 1) accv += __shfl_xor(accv, m);
    out[b * VOCAB + lane] = accp + pb[lane];
    if (lane == 0) out[BATCH * VOCAB + b] = accv + vb[0];
}

extern "C" void kernel_launch(void* const* d_in, const int* in_sizes, int n_in,
                              void* d_out, int out_size, void* d_ws, size_t ws_size,
                              hipStream_t stream) {
    const int*   x      = (const int*)d_in[0];
    const int*   step   = (const int*)d_in[1];
    const float* tok    = (const float*)d_in[2];
    const float* se     = (const float*)d_in[3];
    const float* qkv_w  = (const float*)d_in[4];
    const float* qkv_b  = (const float*)d_in[5];
    const float* out_w  = (const float*)d_in[6];
    const float* out_b  = (const float*)d_in[7];
    const float* relb   = (const float*)d_in[8];
    const float* w1     = (const float*)d_in[9];
    const float* b1     = (const float*)d_in[10];
    const float* w2     = (const float*)d_in[11];
    const float* b2     = (const float*)d_in[12];
    const float* ln1g   = (const float*)d_in[13];
    const float* ln1b   = (const float*)d_in[14];
    const float* ln2g   = (const float*)d_in[15];
    const float* ln2b   = (const float*)d_in[16];
    const float* lnog   = (const float*)d_in[17];
    const float* lnob   = (const float*)d_in[18];
    const float* pw     = (const float*)d_in[19];
    const float* pb     = (const float*)d_in[20];
    const float* vw     = (const float*)d_in[21];
    const float* vb     = (const float*)d_in[22];

    float* out = (float*)d_out;
    float* h = out + BATCH * VOCAB + BATCH;       // h region: [16384,1024] fp32

    char* ws = (char*)d_ws;
    f16* hb     = (f16*)(ws);                                  // 33,554,432 B
    f16* uni    = (f16*)(ws + 33554432);                       // qkv16 / ffn16 union
    f16* qkv16  = uni;
    f16* ffn16  = uni;
    f16* ctx16  = (f16*)(ws + 167772160);
    f16* wqb    = (f16*)(ws + 201326592);
    f16* wob    = (f16*)(ws + 207618048);
    f16* w1b    = (f16*)(ws + 209715200);
    f16* w2b    = (f16*)(ws + 218103808);
    float* pooled = (float*)(ws + 226492416);

    embed_k<<<MS, 256, 0, stream>>>(x, step, tok, se, h, hb);

    for (int l = 0; l < NLAYER; ++l) {
        cvt_k<<<3072, 256, 0, stream>>>(qkv_w + (size_t)l * 3145728, wqb, 786432);
        cvt_k<<<1024, 256, 0, stream>>>(out_w + (size_t)l * 1048576, wob, 262144);
        cvt_k<<<4096, 256, 0, stream>>>(w1 + (size_t)l * 4194304, w1b, 1048576);
        cvt_k<<<4096, 256, 0, stream>>>(w2 + (size_t)l * 4194304, w2b, 1048576);

        gemm_k<0><<<dim3(12, 64), 512, 0, stream>>>(hb, wqb, qkv_b + l * 3072, qkv16, nullptr, MS, 3072, 1024);
        attn_k<<<dim3(NHEAD, BATCH), 64, 0, stream>>>(qkv16, relb + l * 127, ctx16);
        gemm_k<2><<<dim3(4, 64), 512, 0, stream>>>(ctx16, wob, out_b + l * 1024, nullptr, h, MS, 1024, 1024);
        ln_k<<<MS, 256, 0, stream>>>(h, ln1g + l * 1024, ln1b + l * 1024, hb, 1);
        gemm_k<1><<<dim3(16, 64), 512, 0, stream>>>(hb, w1b, b1 + l * 4096, ffn16, nullptr, MS, 4096, 1024);
        gemm_k<2><<<dim3(4, 64), 512, 0, stream>>>(ffn16, w2b, b2 + l * 1024, nullptr, h, MS, 1024, 4096);
        ln_k<<<MS, 256, 0, stream>>>(h, ln2g + l * 1024, ln2b + l * 1024, hb, 1);
    }

    ln_k<<<MS, 256, 0, stream>>>(h, lnog, lnob, hb, 0);
    pool_k<<<BATCH, 256, 0, stream>>>(h, pooled);
    head_k<<<BATCH, 64, 0, stream>>>(pooled, pw, pb, vw, vb, out);
}

// Round 6
// 5818.002 us; speedup vs baseline: 1.0757x; 1.0150x over previous
//
#include <hip/hip_runtime.h>
#include <math.h>

typedef _Float16 f16;
typedef _Float16 f16x8 __attribute__((ext_vector_type(8)));
typedef _Float16 f16x4 __attribute__((ext_vector_type(4)));
typedef float floatx4 __attribute__((ext_vector_type(4)));

#define BATCH 256
#define SEQ 64
#define DMODEL 1024
#define NHEAD 16
#define HDIM 64
#define VOCAB 64
#define DFF 4096
#define NLAYER 8
#define MS (BATCH*SEQ)   // 16384 rows

#define GPTR(p) ((const __attribute__((address_space(1))) void*)(p))
#define LPTR(p) ((__attribute__((address_space(3))) void*)(p))

__device__ __forceinline__ floatx4 mfma16(f16x8 a, f16x8 b, floatx4 c) {
    return __builtin_amdgcn_mfma_f32_16x16x32_f16(a, b, c, 0, 0, 0);
}

__device__ __forceinline__ float gelu_f(float x) {
    return 0.5f * x * (1.f + erff(x * 0.70710678118654752f));
}

// ---------------- embed ------------------------------------------------------
__global__ __launch_bounds__(256) void embed_k(const int* __restrict__ x, const int* __restrict__ step,
                                               const float* __restrict__ tok, const float* __restrict__ se,
                                               float* __restrict__ h, f16* __restrict__ hb) {
    int row = blockIdx.x;
    int t = threadIdx.x;
    int id = x[row];
    int si = min(max(step[0], 0), 63);
    float4 a = ((const float4*)(tok + (size_t)id * DMODEL))[t];
    float4 b = ((const float4*)(se + (size_t)si * DMODEL))[t];
    float4 o;
    o.x = a.x + b.x; o.y = a.y + b.y; o.z = a.z + b.z; o.w = a.w + b.w;
    ((float4*)(h + (size_t)row * DMODEL))[t] = o;
    f16x4 hv; hv[0] = (f16)o.x; hv[1] = (f16)o.y; hv[2] = (f16)o.z; hv[3] = (f16)o.w;
    ((f16x4*)(hb + (size_t)row * DMODEL))[t] = hv;
}

// ---------------- fp32 -> f16 convert ----------------------------------------
__global__ __launch_bounds__(256) void cvt_k(const float* __restrict__ src, f16* __restrict__ dst, int n4) {
    int i = blockIdx.x * 256 + threadIdx.x;
    if (i < n4) {
        float4 v = ((const float4*)src)[i];
        f16x4 o; o[0] = (f16)v.x; o[1] = (f16)v.y; o[2] = (f16)v.z; o[3] = (f16)v.w;
        ((f16x4*)dst)[i] = o;
    }
}

// ---------------- GEMM: C[M,N] = A[M,K] @ Bw[N,K]^T --------------------------
// 128x128 tile, BK=64, 2x32KB double-buffer -> 2 blocks/CU (cross-block overlap).
// T3 minimal 2-phase: STAGE(buf^1,t+1) first, ds_reads, MFMA, one vmcnt(0)+barrier.
// T2 XOR swizzle: physical 16B-block p at row r holds logical p^(r&7).
// 4 waves (2M x 2N), per-wave 64x64 output (acc[4][4]).
// MODE 0: store f16 (bias)  MODE 1: store f16 (bias+gelu)  MODE 2: h += acc+bias (fp32)
template<int MODE>
__global__ __launch_bounds__(256, 2) void gemm_k(const f16* __restrict__ A, const f16* __restrict__ Bw,
                                                 const float* __restrict__ bias,
                                                 f16* __restrict__ Cb, float* __restrict__ Hacc,
                                                 int M, int N, int K) {
    __shared__ f16 smem[32768];   // [2][16384]: per buf A[128][64] | B[128][64] = 32 KB

    const int tid = threadIdx.x;
    const int lane = tid & 63;
    const int wave = tid >> 6;
    const int wm = wave >> 1, wn = wave & 1;     // 2 x 2 wave grid
    const int lr = lane & 15, lg = lane >> 4;
    const int sa = lr & 7;

    // bijective XCD-aware block swizzle (all grids have nwg % 8 == 0)
    const unsigned nx = gridDim.x;
    const unsigned nwg = nx * gridDim.y;
    unsigned flat = blockIdx.y * nx + blockIdx.x;
    flat = (flat & 7u) * (nwg >> 3) + (flat >> 3);
    const int m0 = (int)(flat / nx) * 128;
    const int n0 = (int)(flat % nx) * 128;

    floatx4 acc[4][4] = {};

    // staging: thread t covers (row = 32c + (t>>3), 16B-block = t&7); pre-swizzled source.
    const int srow = tid >> 3;          // 0..31
    const int scbs = (tid & 7) ^ (srow & 7);
    const f16* Asrc = A + (size_t)(m0 + srow) * K + scbs * 8;
    const f16* Bsrc = Bw + (size_t)(n0 + srow) * K + scbs * 8;
    const int ldsw = wave * 512;        // wave-uniform f16 base (HW adds lane*16B)

#define STAGE(bi, tt) do {                                                                        \
    const f16* _a = Asrc + (size_t)(tt) * 64;                                                     \
    const f16* _b = Bsrc + (size_t)(tt) * 64;                                                     \
    f16* _l = smem + ((bi) << 14) + ldsw;                                                         \
    __builtin_amdgcn_global_load_lds(GPTR(_a),                  LPTR(_l),         16, 0, 0);      \
    __builtin_amdgcn_global_load_lds(GPTR(_a + 32 * (size_t)K), LPTR(_l + 2048),  16, 0, 0);      \
    __builtin_amdgcn_global_load_lds(GPTR(_a + 64 * (size_t)K), LPTR(_l + 4096),  16, 0, 0);      \
    __builtin_amdgcn_global_load_lds(GPTR(_a + 96 * (size_t)K), LPTR(_l + 6144),  16, 0, 0);      \
    __builtin_amdgcn_global_load_lds(GPTR(_b),                  LPTR(_l + 8192),  16, 0, 0);      \
    __builtin_amdgcn_global_load_lds(GPTR(_b + 32 * (size_t)K), LPTR(_l + 10240), 16, 0, 0);      \
    __builtin_amdgcn_global_load_lds(GPTR(_b + 64 * (size_t)K), LPTR(_l + 12288), 16, 0, 0);      \
    __builtin_amdgcn_global_load_lds(GPTR(_b + 96 * (size_t)K), LPTR(_l + 14336), 16, 0, 0);      \
} while (0)

    const int NT = K >> 6;

    // prologue
    STAGE(0, 0);
    asm volatile("s_waitcnt vmcnt(0)" ::: "memory");
    __builtin_amdgcn_s_barrier();

    int buf = 0;
    for (int t = 0; t < NT; ++t) {
        if (t + 1 < NT) STAGE(buf ^ 1, t + 1);    // issue next tile FIRST

        const f16* Ab = smem + (buf << 14);
        const f16* Bb = Ab + 8192;
        f16x8 af[8], bf[8];
#pragma unroll
        for (int kh = 0; kh < 2; ++kh)
#pragma unroll
            for (int mi = 0; mi < 4; ++mi)
                af[kh * 4 + mi] = *(const f16x8*)(Ab + (wm * 64 + mi * 16 + lr) * 64
                                                  + (((kh * 4 + lg) ^ sa) << 3));
#pragma unroll
        for (int kh = 0; kh < 2; ++kh)
#pragma unroll
            for (int ni = 0; ni < 4; ++ni)
                bf[kh * 4 + ni] = *(const f16x8*)(Bb + (wn * 64 + ni * 16 + lr) * 64
                                                  + (((kh * 4 + lg) ^ sa) << 3));

        __builtin_amdgcn_s_setprio(1);
#pragma unroll
        for (int kh = 0; kh < 2; ++kh)
#pragma unroll
            for (int mi = 0; mi < 4; ++mi)
#pragma unroll
                for (int ni = 0; ni < 4; ++ni)
                    acc[mi][ni] = mfma16(af[kh * 4 + mi], bf[kh * 4 + ni], acc[mi][ni]);
        __builtin_amdgcn_s_setprio(0);

        if (t + 1 < NT) { asm volatile("s_waitcnt vmcnt(0)" ::: "memory"); }
        __builtin_amdgcn_s_barrier();
        buf ^= 1;
    }
#undef STAGE

    if (MODE == 2) {
#pragma unroll
        for (int ni = 0; ni < 4; ++ni) {
            int cc = n0 + wn * 64 + ni * 16 + lr;
            float bvl = bias[cc];
#pragma unroll
            for (int mi = 0; mi < 4; ++mi)
#pragma unroll
                for (int j = 0; j < 4; ++j) {
                    int rr = m0 + wm * 64 + mi * 16 + lg * 4 + j;
                    float* p = Hacc + (size_t)rr * N + cc;
                    *p += acc[mi][ni][j] + bvl;
                }
        }
    } else {
        // wave-private 64x64 f16 scratch (no barriers needed)
        f16* scr = smem + wave * 4096;
        float bsv[4];
#pragma unroll
        for (int ni = 0; ni < 4; ++ni) bsv[ni] = bias[n0 + wn * 64 + ni * 16 + lr];
#pragma unroll
        for (int mi = 0; mi < 4; ++mi)
#pragma unroll
            for (int ni = 0; ni < 4; ++ni)
#pragma unroll
                for (int j = 0; j < 4; ++j) {
                    int r = mi * 16 + lg * 4 + j;
                    int c = ni * 16 + lr;
                    float v = acc[mi][ni][j] + bsv[ni];
                    if (MODE == 1) v = gelu_f(v);
                    scr[r * 64 + (((c >> 3) ^ (r & 7)) * 8) + (c & 7)] = (f16)v;
                }
        int gr = m0 + wm * 64 + lane;
        f16* dst = Cb + (size_t)gr * N + n0 + wn * 64;
#pragma unroll
        for (int i = 0; i < 8; ++i) {
            f16x8 v = *(const f16x8*)(scr + lane * 64 + ((i ^ (lane & 7)) * 8));
            *(f16x8*)(dst + i * 8) = v;
        }
    }
}

// ---------------- attention: one wave per (b,h) -------------------------------
__global__ __launch_bounds__(64) void attn_k(const f16* __restrict__ qkv, const float* __restrict__ rb,
                                             f16* __restrict__ ctx) {
    const int hh = blockIdx.x;
    const int bb = blockIdx.y;
    const int lane = threadIdx.x;
    __shared__ float rbs[128];
    __shared__ f16 Vt[64][72];
    __shared__ f16 Pl[64][72];

    for (int i = lane; i < 127; i += 64) rbs[i] = rb[i];

    const f16* vrow = qkv + (size_t)(bb * 64 + lane) * 3072 + 2048 + hh * 64;
#pragma unroll
    for (int i = 0; i < 8; ++i) {
        f16x8 v = *(const f16x8*)(vrow + i * 8);
#pragma unroll
        for (int j = 0; j < 8; ++j) Vt[i * 8 + j][lane] = v[j];
    }
    __syncthreads();

    const int lr = lane & 15, lg = lane >> 4;
    floatx4 sacc[4][4] = {};
    const f16* qbase = qkv + (size_t)(bb * 64) * 3072 + hh * 64;
#pragma unroll
    for (int kk = 0; kk < 64; kk += 32) {
        f16x8 qa[4], kb[4];
#pragma unroll
        for (int mf = 0; mf < 4; ++mf)
            qa[mf] = *(const f16x8*)(qbase + (size_t)(mf * 16 + lr) * 3072 + kk + lg * 8);
#pragma unroll
        for (int nf = 0; nf < 4; ++nf)
            kb[nf] = *(const f16x8*)(qbase + 1024 + (size_t)(nf * 16 + lr) * 3072 + kk + lg * 8);
#pragma unroll
        for (int mf = 0; mf < 4; ++mf)
#pragma unroll
            for (int nf = 0; nf < 4; ++nf)
                sacc[mf][nf] = mfma16(qa[mf], kb[nf], sacc[mf][nf]);
    }

#pragma unroll
    for (int mf = 0; mf < 4; ++mf) {
#pragma unroll
        for (int j = 0; j < 4; ++j) {
            int qrow = mf * 16 + lg * 4 + j;
            float v0 = sacc[mf][0][j] * 0.125f + rbs[qrow - (0  + lr) + 63];
            float v1 = sacc[mf][1][j] * 0.125f + rbs[qrow - (16 + lr) + 63];
            float v2 = sacc[mf][2][j] * 0.125f + rbs[qrow - (32 + lr) + 63];
            float v3 = sacc[mf][3][j] * 0.125f + rbs[qrow - (48 + lr) + 63];
            float mx = fmaxf(fmaxf(v0, v1), fmaxf(v2, v3));
            for (int m = 1; m < 16; m <<= 1) mx = fmaxf(mx, __shfl_xor(mx, m));
            v0 = __expf(v0 - mx); v1 = __expf(v1 - mx); v2 = __expf(v2 - mx); v3 = __expf(v3 - mx);
            float sum = v0 + v1 + v2 + v3;
            for (int m = 1; m < 16; m <<= 1) sum += __shfl_xor(sum, m);
            float inv = 1.f / sum;
            Pl[qrow][0  + lr] = (f16)(v0 * inv);
            Pl[qrow][16 + lr] = (f16)(v1 * inv);
            Pl[qrow][32 + lr] = (f16)(v2 * inv);
            Pl[qrow][48 + lr] = (f16)(v3 * inv);
        }
    }
    __syncthreads();

    floatx4 oacc[4][4] = {};
#pragma unroll
    for (int kk = 0; kk < 64; kk += 32) {
        f16x8 pa[4], vb[4];
#pragma unroll
        for (int mf = 0; mf < 4; ++mf) pa[mf] = *(const f16x8*)&Pl[mf * 16 + lr][kk + lg * 8];
#pragma unroll
        for (int nf = 0; nf < 4; ++nf) vb[nf] = *(const f16x8*)&Vt[nf * 16 + lr][kk + lg * 8];
#pragma unroll
        for (int mf = 0; mf < 4; ++mf)
#pragma unroll
            for (int nf = 0; nf < 4; ++nf)
                oacc[mf][nf] = mfma16(pa[mf], vb[nf], oacc[mf][nf]);
    }
    __syncthreads();
#pragma unroll
    for (int mf = 0; mf < 4; ++mf)
#pragma unroll
        for (int nf = 0; nf < 4; ++nf)
#pragma unroll
            for (int j = 0; j < 4; ++j)
                Pl[mf * 16 + lg * 4 + j][nf * 16 + lr] = (f16)oacc[mf][nf][j];
    __syncthreads();
    f16* crow = ctx + (size_t)(bb * 64 + lane) * DMODEL + hh * 64;
#pragma unroll
    for (int i = 0; i < 8; ++i) {
        f16x8 v = *(const f16x8*)&Pl[lane][i * 8];
        *(f16x8*)(crow + i * 8) = v;
    }
}

// ---------------- LayerNorm in-place on h, optionally emit f16 copy -----------
__global__ __launch_bounds__(256) void ln_k(float* __restrict__ h, const float* __restrict__ g,
                                            const float* __restrict__ b, f16* __restrict__ hb, int emit) {
    int row = blockIdx.x;
    int t = threadIdx.x;
    float4 v = ((const float4*)(h + (size_t)row * DMODEL))[t];
    float s = v.x + v.y + v.z + v.w;
    float ss = v.x * v.x + v.y * v.y + v.z * v.z + v.w * v.w;
    for (int m = 1; m < 64; m <<= 1) { s += __shfl_xor(s, m); ss += __shfl_xor(ss, m); }
    __shared__ float red[8];
    if ((t & 63) == 0) { red[(t >> 6) * 2] = s; red[(t >> 6) * 2 + 1] = ss; }
    __syncthreads();
    s = red[0] + red[2] + red[4] + red[6];
    ss = red[1] + red[3] + red[5] + red[7];
    float mean = s * (1.f / 1024.f);
    float var = ss * (1.f / 1024.f) - mean * mean;
    float rstd = rsqrtf(var + 1e-5f);
    float4 gg = ((const float4*)g)[t];
    float4 bb = ((const float4*)b)[t];
    float4 o;
    o.x = (v.x - mean) * rstd * gg.x + bb.x;
    o.y = (v.y - mean) * rstd * gg.y + bb.y;
    o.z = (v.z - mean) * rstd * gg.z + bb.z;
    o.w = (v.w - mean) * rstd * gg.w + bb.w;
    ((float4*)(h + (size_t)row * DMODEL))[t] = o;
    if (emit) {
        f16x4 hv; hv[0] = (f16)o.x; hv[1] = (f16)o.y; hv[2] = (f16)o.z; hv[3] = (f16)o.w;
        ((f16x4*)(hb + (size_t)row * DMODEL))[t] = hv;
    }
}

// ---------------- mean over S -------------------------------------------------
__global__ __launch_bounds__(256) void pool_k(const float* __restrict__ h, float* __restrict__ pooled) {
    int b = blockIdx.x;
    int t = threadIdx.x;
    float sx = 0, sy = 0, sz = 0, sw = 0;
    for (int s = 0; s < SEQ; ++s) {
        float4 v = ((const float4*)(h + (size_t)(b * SEQ + s) * DMODEL))[t];
        sx += v.x; sy += v.y; sz += v.z; sw += v.w;
    }
    float4 o; o.x = sx * (1.f / 64.f); o.y = sy * (1.f / 64.f); o.z = sz * (1.f / 64.f); o.w = sw * (1.f / 64.f);
    ((float4*)(pooled + (size_t)b * DMODEL))[t] = o;
}

// ---------------- policy / value heads ---------------------------------------
__global__ __launch_bounds__(64) void head_k(const float* __restrict__ pooled, const float* __restrict__ pw,
                                             const float* __restrict__ pb, const float* __restrict__ vw,
                                             const float* __restrict__ vb, float* __restrict__ out) {
    int b = blockIdx.x;
    int lane = threadIdx.x;
    const float* pr = pooled + (size_t)b * DMODEL;
    const float* wr = pw + (size_t)lane * DMODEL;
    float accp = 0.f;
    for (int d = 0; d < DMODEL; d += 4) {
        float4 x = *(const float4*)(pr + d);
        float4 w = *(const float4*)(wr + d);
        accp += x.x * w.x + x.y * w.y + x.z * w.z + x.w * w.w;
    }
    float accv = 0.f;
    for (int d = lane * 4; d < DMODEL; d += 256) {
        float4 x = *(const float4*)(pr + d);
        float4 w = *(const float4*)(vw + d);
        accv += x.x * w.x + x.y * w.y + x.z * w.z + x.w * w.w;
    }
    for (int m = 1; m < 64; m <<= 1) accv += __shfl_xor(accv, m);
    out[b * VOCAB + lane] = accp + pb[lane];
    if (lane == 0) out[BATCH * VOCAB + b] = accv + vb[0];
}

extern "C" void kernel_launch(void* const* d_in, const int* in_sizes, int n_in,
                              void* d_out, int out_size, void* d_ws, size_t ws_size,
                              hipStream_t stream) {
    const int*   x      = (const int*)d_in[0];
    const int*   step   = (const int*)d_in[1];
    const float* tok    = (const float*)d_in[2];
    const float* se     = (const float*)d_in[3];
    const float* qkv_w  = (const float*)d_in[4];
    const float* qkv_b  = (const float*)d_in[5];
    const float* out_w  = (const float*)d_in[6];
    const float* out_b  = (const float*)d_in[7];
    const float* relb   = (const float*)d_in[8];
    const float* w1     = (const float*)d_in[9];
    const float* b1     = (const float*)d_in[10];
    const float* w2     = (const float*)d_in[11];
    const float* b2     = (const float*)d_in[12];
    const float* ln1g   = (const float*)d_in[13];
    const float* ln1b   = (const float*)d_in[14];
    const float* ln2g   = (const float*)d_in[15];
    const float* ln2b   = (const float*)d_in[16];
    const float* lnog   = (const float*)d_in[17];
    const float* lnob   = (const float*)d_in[18];
    const float* pw     = (const float*)d_in[19];
    const float* pb     = (const float*)d_in[20];
    const float* vw     = (const float*)d_in[21];
    const float* vb     = (const float*)d_in[22];

    float* out = (float*)d_out;
    float* h = out + BATCH * VOCAB + BATCH;       // h region: [16384,1024] fp32

    char* ws = (char*)d_ws;
    f16* hb     = (f16*)(ws);                                  // 33,554,432 B
    f16* uni    = (f16*)(ws + 33554432);                       // qkv16 / ffn16 union
    f16* qkv16  = uni;
    f16* ffn16  = uni;
    f16* ctx16  = (f16*)(ws + 167772160);
    f16* wqb    = (f16*)(ws + 201326592);
    f16* wob    = (f16*)(ws + 207618048);
    f16* w1b    = (f16*)(ws + 209715200);
    f16* w2b    = (f16*)(ws + 218103808);
    float* pooled = (float*)(ws + 226492416);

    embed_k<<<MS, 256, 0, stream>>>(x, step, tok, se, h, hb);

    for (int l = 0; l < NLAYER; ++l) {
        cvt_k<<<3072, 256, 0, stream>>>(qkv_w + (size_t)l * 3145728, wqb, 786432);
        cvt_k<<<1024, 256, 0, stream>>>(out_w + (size_t)l * 1048576, wob, 262144);
        cvt_k<<<4096, 256, 0, stream>>>(w1 + (size_t)l * 4194304, w1b, 1048576);
        cvt_k<<<4096, 256, 0, stream>>>(w2 + (size_t)l * 4194304, w2b, 1048576);

        gemm_k<0><<<dim3(24, 128), 256, 0, stream>>>(hb, wqb, qkv_b + l * 3072, qkv16, nullptr, MS, 3072, 1024);
        attn_k<<<dim3(NHEAD, BATCH), 64, 0, stream>>>(qkv16, relb + l * 127, ctx16);
        gemm_k<2><<<dim3(8, 128), 256, 0, stream>>>(ctx16, wob, out_b + l * 1024, nullptr, h, MS, 1024, 1024);
        ln_k<<<MS, 256, 0, stream>>>(h, ln1g + l * 1024, ln1b + l * 1024, hb, 1);
        gemm_k<1><<<dim3(32, 128), 256, 0, stream>>>(hb, w1b, b1 + l * 4096, ffn16, nullptr, MS, 4096, 1024);
        gemm_k<2><<<dim3(8, 128), 256, 0, stream>>>(ffn16, w2b, b2 + l * 1024, nullptr, h, MS, 1024, 4096);
        ln_k<<<MS, 256, 0, stream>>>(h, ln2g + l * 1024, ln2b + l * 1024, hb, 1);
    }

    ln_k<<<MS, 256, 0, stream>>>(h, lnog, lnob, hb, 0);
    pool_k<<<BATCH, 256, 0, stream>>>(h, pooled);
    head_k<<<BATCH, 64, 0, stream>>>(pooled, pw, pb, vw, vb, out);
}

// Round 7
// 5011.618 us; speedup vs baseline: 1.2487x; 1.1609x over previous
//
#include <hip/hip_runtime.h>
#include <math.h>

typedef _Float16 f16;
typedef _Float16 f16x8 __attribute__((ext_vector_type(8)));
typedef _Float16 f16x4 __attribute__((ext_vector_type(4)));
typedef float floatx4 __attribute__((ext_vector_type(4)));

#define BATCH 256
#define SEQ 64
#define DMODEL 1024
#define NHEAD 16
#define HDIM 64
#define VOCAB 64
#define DFF 4096
#define NLAYER 8
#define MS (BATCH*SEQ)   // 16384 rows

#define GPTR(p) ((const __attribute__((address_space(1))) void*)(p))
#define LPTR(p) ((__attribute__((address_space(3))) void*)(p))

__device__ __forceinline__ floatx4 mfma16(f16x8 a, f16x8 b, floatx4 c) {
    return __builtin_amdgcn_mfma_f32_16x16x32_f16(a, b, c, 0, 0, 0);
}

__device__ __forceinline__ float gelu_f(float x) {
    return 0.5f * x * (1.f + erff(x * 0.70710678118654752f));
}

// ---------------- embed: r = f16(tok[x] + step_embed[step]) -------------------
__global__ __launch_bounds__(256) void embed_k(const int* __restrict__ x, const int* __restrict__ step,
                                               const float* __restrict__ tok, const float* __restrict__ se,
                                               f16* __restrict__ r) {
    int row = blockIdx.x;
    int t = threadIdx.x;
    int id = x[row];
    int si = min(max(step[0], 0), 63);
    float4 a = ((const float4*)(tok + (size_t)id * DMODEL))[t];
    float4 b = ((const float4*)(se + (size_t)si * DMODEL))[t];
    f16x4 hv; hv[0] = (f16)(a.x + b.x); hv[1] = (f16)(a.y + b.y);
    hv[2] = (f16)(a.z + b.z); hv[3] = (f16)(a.w + b.w);
    ((f16x4*)(r + (size_t)row * DMODEL))[t] = hv;
}

// ---------------- fp32 -> f16 convert, all 4 weight mats of a layer ----------
__global__ __launch_bounds__(256) void cvt4_k(const float* __restrict__ qw, const float* __restrict__ ow,
                                              const float* __restrict__ w1, const float* __restrict__ w2,
                                              f16* __restrict__ dq, f16* __restrict__ dO,
                                              f16* __restrict__ d1, f16* __restrict__ d2) {
    int gid = blockIdx.x * 256 + threadIdx.x;   // grid covers 3,145,728 float4s
    const float4* s; f16x4* d; int off;
    if (gid < 786432)        { s = (const float4*)qw; d = (f16x4*)dq; off = gid; }
    else if (gid < 1048576)  { s = (const float4*)ow; d = (f16x4*)dO; off = gid - 786432; }
    else if (gid < 2097152)  { s = (const float4*)w1; d = (f16x4*)d1; off = gid - 1048576; }
    else                     { s = (const float4*)w2; d = (f16x4*)d2; off = gid - 2097152; }
    float4 v = s[off];
    f16x4 o; o[0] = (f16)v.x; o[1] = (f16)v.y; o[2] = (f16)v.z; o[3] = (f16)v.w;
    d[off] = o;
}

// ---------------- GEMM: C[M,N] = A[M,K] @ Bw[N,K]^T --------------------------
// 128x128 tile, BK=64, 2x32KB double-buffer -> 2 blocks/CU, K-loop unrolled x2.
// T2 XOR swizzle: physical 16B-block p at row r holds logical p^(r&7).
// 4 waves (2M x 2N), per-wave 64x64 output (acc[4][4]).
// MODE 0: store f16 (bias)   MODE 1: store f16 (bias+gelu)
// MODE 2: res = Rres + acc + bias -> f16 ResOut + per-row partial (sum,sumsq)
template<int MODE>
__global__ __launch_bounds__(256, 2) void gemm_k(const f16* __restrict__ A, const f16* __restrict__ Bw,
                                                 const float* __restrict__ bias,
                                                 f16* __restrict__ Cb,
                                                 const f16* __restrict__ Rres, f16* __restrict__ ResOut,
                                                 float2* __restrict__ Part,
                                                 int M, int N, int K) {
    __shared__ f16 smem[32768];   // [2][16384]: per buf A[128][64] | B[128][64] = 32 KB

    const int tid = threadIdx.x;
    const int lane = tid & 63;
    const int wave = tid >> 6;
    const int wm = wave >> 1, wn = wave & 1;     // 2 x 2 wave grid
    const int lr = lane & 15, lg = lane >> 4;
    const int sa = lr & 7;

    // bijective XCD-aware block swizzle (all grids have nwg % 8 == 0)
    const unsigned nx = gridDim.x;
    const unsigned nwg = nx * gridDim.y;
    unsigned flat = blockIdx.y * nx + blockIdx.x;
    flat = (flat & 7u) * (nwg >> 3) + (flat >> 3);
    const int m0 = (int)(flat / nx) * 128;
    const int n0 = (int)(flat % nx) * 128;

    floatx4 acc[4][4] = {};

    // staging: thread t covers (row = 32c + (t>>3), 16B-block = t&7); pre-swizzled source.
    const int srow = tid >> 3;          // 0..31
    const int scbs = (tid & 7) ^ (srow & 7);
    const f16* Asrc = A + (size_t)(m0 + srow) * K + scbs * 8;
    const f16* Bsrc = Bw + (size_t)(n0 + srow) * K + scbs * 8;
    const int ldsw = wave * 512;        // wave-uniform f16 base (HW adds lane*16B)

#define STAGE(bi, tt) do {                                                                        \
    const f16* _a = Asrc + (size_t)(tt) * 64;                                                     \
    const f16* _b = Bsrc + (size_t)(tt) * 64;                                                     \
    f16* _l = smem + ((bi) << 14) + ldsw;                                                         \
    __builtin_amdgcn_global_load_lds(GPTR(_a),                  LPTR(_l),         16, 0, 0);      \
    __builtin_amdgcn_global_load_lds(GPTR(_a + 32 * (size_t)K), LPTR(_l + 2048),  16, 0, 0);      \
    __builtin_amdgcn_global_load_lds(GPTR(_a + 64 * (size_t)K), LPTR(_l + 4096),  16, 0, 0);      \
    __builtin_amdgcn_global_load_lds(GPTR(_a + 96 * (size_t)K), LPTR(_l + 6144),  16, 0, 0);      \
    __builtin_amdgcn_global_load_lds(GPTR(_b),                  LPTR(_l + 8192),  16, 0, 0);      \
    __builtin_amdgcn_global_load_lds(GPTR(_b + 32 * (size_t)K), LPTR(_l + 10240), 16, 0, 0);      \
    __builtin_amdgcn_global_load_lds(GPTR(_b + 64 * (size_t)K), LPTR(_l + 12288), 16, 0, 0);      \
    __builtin_amdgcn_global_load_lds(GPTR(_b + 96 * (size_t)K), LPTR(_l + 14336), 16, 0, 0);      \
} while (0)

#define TILE_BODY(t_, bi) do {                                                                    \
    if ((t_) + 1 < NT) STAGE((bi) ^ 1, (t_) + 1);                                                 \
    const f16* Ab = smem + ((bi) << 14);                                                          \
    const f16* Bb = Ab + 8192;                                                                    \
    f16x8 af[8], bf[8];                                                                           \
    _Pragma("unroll") for (int kh = 0; kh < 2; ++kh)                                              \
    _Pragma("unroll") for (int mi = 0; mi < 4; ++mi)                                              \
        af[kh * 4 + mi] = *(const f16x8*)(Ab + (wm * 64 + mi * 16 + lr) * 64                      \
                                          + (((kh * 4 + lg) ^ sa) << 3));                         \
    _Pragma("unroll") for (int kh = 0; kh < 2; ++kh)                                              \
    _Pragma("unroll") for (int ni = 0; ni < 4; ++ni)                                              \
        bf[kh * 4 + ni] = *(const f16x8*)(Bb + (wn * 64 + ni * 16 + lr) * 64                      \
                                          + (((kh * 4 + lg) ^ sa) << 3));                         \
    __builtin_amdgcn_s_setprio(1);                                                                \
    _Pragma("unroll") for (int kh = 0; kh < 2; ++kh)                                              \
    _Pragma("unroll") for (int mi = 0; mi < 4; ++mi)                                              \
    _Pragma("unroll") for (int ni = 0; ni < 4; ++ni)                                              \
        acc[mi][ni] = mfma16(af[kh * 4 + mi], bf[kh * 4 + ni], acc[mi][ni]);                      \
    __builtin_amdgcn_s_setprio(0);                                                                \
    if ((t_) + 1 < NT) { asm volatile("s_waitcnt vmcnt(0)" ::: "memory"); }                       \
    __builtin_amdgcn_s_barrier();                                                                 \
} while (0)

    const int NT = K >> 6;   // even for all our K (16 or 64)

    STAGE(0, 0);
    asm volatile("s_waitcnt vmcnt(0)" ::: "memory");
    __builtin_amdgcn_s_barrier();

    for (int t = 0; t < NT; t += 2) {
        TILE_BODY(t, 0);
        TILE_BODY(t + 1, 1);
    }
#undef STAGE
#undef TILE_BODY

    if (MODE == 2) {
        // bounce through wave-private LDS, then coalesced read-out with
        // residual add + per-row (sum, sumsq) partials.
        float bsv[4];
#pragma unroll
        for (int ni = 0; ni < 4; ++ni) bsv[ni] = bias[n0 + wn * 64 + ni * 16 + lr];
        f16* scr = smem + wave * 4096;
#pragma unroll
        for (int mi = 0; mi < 4; ++mi)
#pragma unroll
            for (int ni = 0; ni < 4; ++ni)
#pragma unroll
                for (int j = 0; j < 4; ++j) {
                    int rr = mi * 16 + lg * 4 + j;
                    int cc = ni * 16 + lr;
                    scr[rr * 64 + (((cc >> 3) ^ (rr & 7)) * 8) + (cc & 7)]
                        = (f16)(acc[mi][ni][j] + bsv[ni]);
                }
        int gr = m0 + wm * 64 + lane;
        const f16* rrow = Rres + (size_t)gr * N + n0 + wn * 64;
        f16* orow = ResOut + (size_t)gr * N + n0 + wn * 64;
        float s = 0.f, ss = 0.f;
#pragma unroll
        for (int i = 0; i < 8; ++i) {
            f16x8 a = *(const f16x8*)(scr + lane * 64 + ((i ^ (lane & 7)) * 8));
            f16x8 rv = *(const f16x8*)(rrow + i * 8);
            f16x8 o;
#pragma unroll
            for (int k = 0; k < 8; ++k) {
                float v = (float)a[k] + (float)rv[k];
                s += v; ss += v * v;
                o[k] = (f16)v;
            }
            *(f16x8*)(orow + i * 8) = o;
        }
        float* red = (float*)(smem + 16384);   // bytes 32768.. (free region)
        if (wn == 1) { red[(wm * 64 + lane) * 2] = s; red[(wm * 64 + lane) * 2 + 1] = ss; }
        __syncthreads();
        if (wn == 0) {
            float s2 = red[(wm * 64 + lane) * 2], ss2 = red[(wm * 64 + lane) * 2 + 1];
            Part[(size_t)gr * (N >> 7) + (n0 >> 7)] = float2{s + s2, ss + ss2};
        }
    } else {
        // wave-private 64x64 f16 scratch (no barriers needed)
        f16* scr = smem + wave * 4096;
        float bsv[4];
#pragma unroll
        for (int ni = 0; ni < 4; ++ni) bsv[ni] = bias[n0 + wn * 64 + ni * 16 + lr];
#pragma unroll
        for (int mi = 0; mi < 4; ++mi)
#pragma unroll
            for (int ni = 0; ni < 4; ++ni)
#pragma unroll
                for (int j = 0; j < 4; ++j) {
                    int rr = mi * 16 + lg * 4 + j;
                    int cc = ni * 16 + lr;
                    float v = acc[mi][ni][j] + bsv[ni];
                    if (MODE == 1) v = gelu_f(v);
                    scr[rr * 64 + (((cc >> 3) ^ (rr & 7)) * 8) + (cc & 7)] = (f16)v;
                }
        int gr = m0 + wm * 64 + lane;
        f16* dst = Cb + (size_t)gr * N + n0 + wn * 64;
#pragma unroll
        for (int i = 0; i < 8; ++i) {
            f16x8 v = *(const f16x8*)(scr + lane * 64 + ((i ^ (lane & 7)) * 8));
            *(f16x8*)(dst + i * 8) = v;
        }
    }
}

// ---------------- attention: one wave per (b,h) -------------------------------
__global__ __launch_bounds__(64) void attn_k(const f16* __restrict__ qkv, const float* __restrict__ rb,
                                             f16* __restrict__ ctx) {
    const int hh = blockIdx.x;
    const int bb = blockIdx.y;
    const int lane = threadIdx.x;
    __shared__ float rbs[128];
    __shared__ f16 Vt[64][72];
    __shared__ f16 Pl[64][72];

    for (int i = lane; i < 127; i += 64) rbs[i] = rb[i];

    const f16* vrow = qkv + (size_t)(bb * 64 + lane) * 3072 + 2048 + hh * 64;
#pragma unroll
    for (int i = 0; i < 8; ++i) {
        f16x8 v = *(const f16x8*)(vrow + i * 8);
#pragma unroll
        for (int j = 0; j < 8; ++j) Vt[i * 8 + j][lane] = v[j];
    }
    __syncthreads();

    const int lr = lane & 15, lg = lane >> 4;
    floatx4 sacc[4][4] = {};
    const f16* qbase = qkv + (size_t)(bb * 64) * 3072 + hh * 64;
#pragma unroll
    for (int kk = 0; kk < 64; kk += 32) {
        f16x8 qa[4], kb[4];
#pragma unroll
        for (int mf = 0; mf < 4; ++mf)
            qa[mf] = *(const f16x8*)(qbase + (size_t)(mf * 16 + lr) * 3072 + kk + lg * 8);
#pragma unroll
        for (int nf = 0; nf < 4; ++nf)
            kb[nf] = *(const f16x8*)(qbase + 1024 + (size_t)(nf * 16 + lr) * 3072 + kk + lg * 8);
#pragma unroll
        for (int mf = 0; mf < 4; ++mf)
#pragma unroll
            for (int nf = 0; nf < 4; ++nf)
                sacc[mf][nf] = mfma16(qa[mf], kb[nf], sacc[mf][nf]);
    }

#pragma unroll
    for (int mf = 0; mf < 4; ++mf) {
#pragma unroll
        for (int j = 0; j < 4; ++j) {
            int qrow = mf * 16 + lg * 4 + j;
            float v0 = sacc[mf][0][j] * 0.125f + rbs[qrow - (0  + lr) + 63];
            float v1 = sacc[mf][1][j] * 0.125f + rbs[qrow - (16 + lr) + 63];
            float v2 = sacc[mf][2][j] * 0.125f + rbs[qrow - (32 + lr) + 63];
            float v3 = sacc[mf][3][j] * 0.125f + rbs[qrow - (48 + lr) + 63];
            float mx = fmaxf(fmaxf(v0, v1), fmaxf(v2, v3));
            for (int m = 1; m < 16; m <<= 1) mx = fmaxf(mx, __shfl_xor(mx, m));
            v0 = __expf(v0 - mx); v1 = __expf(v1 - mx); v2 = __expf(v2 - mx); v3 = __expf(v3 - mx);
            float sum = v0 + v1 + v2 + v3;
            for (int m = 1; m < 16; m <<= 1) sum += __shfl_xor(sum, m);
            float inv = 1.f / sum;
            Pl[qrow][0  + lr] = (f16)(v0 * inv);
            Pl[qrow][16 + lr] = (f16)(v1 * inv);
            Pl[qrow][32 + lr] = (f16)(v2 * inv);
            Pl[qrow][48 + lr] = (f16)(v3 * inv);
        }
    }
    __syncthreads();

    floatx4 oacc[4][4] = {};
#pragma unroll
    for (int kk = 0; kk < 64; kk += 32) {
        f16x8 pa[4], vb[4];
#pragma unroll
        for (int mf = 0; mf < 4; ++mf) pa[mf] = *(const f16x8*)&Pl[mf * 16 + lr][kk + lg * 8];
#pragma unroll
        for (int nf = 0; nf < 4; ++nf) vb[nf] = *(const f16x8*)&Vt[nf * 16 + lr][kk + lg * 8];
#pragma unroll
        for (int mf = 0; mf < 4; ++mf)
#pragma unroll
            for (int nf = 0; nf < 4; ++nf)
                oacc[mf][nf] = mfma16(pa[mf], vb[nf], oacc[mf][nf]);
    }
    __syncthreads();
#pragma unroll
    for (int mf = 0; mf < 4; ++mf)
#pragma unroll
        for (int nf = 0; nf < 4; ++nf)
#pragma unroll
            for (int j = 0; j < 4; ++j)
                Pl[mf * 16 + lg * 4 + j][nf * 16 + lr] = (f16)oacc[mf][nf][j];
    __syncthreads();
    f16* crow = ctx + (size_t)(bb * 64 + lane) * DMODEL + hh * 64;
#pragma unroll
    for (int i = 0; i < 8; ++i) {
        f16x8 v = *(const f16x8*)&Pl[lane][i * 8];
        *(f16x8*)(crow + i * 8) = v;
    }
}

// ---------------- LayerNorm from fused partials: out = LN(res) (f16) ---------
__global__ __launch_bounds__(128) void ln_k(const f16* __restrict__ res, const float2* __restrict__ part,
                                            const float* __restrict__ g, const float* __restrict__ b,
                                            f16* __restrict__ out) {
    int row = blockIdx.x;
    int t = threadIdx.x;
    f16x8 rv = ((const f16x8*)(res + (size_t)row * DMODEL))[t];
    float s = 0.f, ss = 0.f;
#pragma unroll
    for (int c = 0; c < 8; ++c) {
        float2 p = part[(size_t)row * 8 + c];
        s += p.x; ss += p.y;
    }
    float mean = s * (1.f / 1024.f);
    float var = ss * (1.f / 1024.f) - mean * mean;
    float rstd = rsqrtf(var + 1e-5f);
    float4 g0 = ((const float4*)g)[t * 2], g1 = ((const float4*)g)[t * 2 + 1];
    float4 b0 = ((const float4*)b)[t * 2], b1 = ((const float4*)b)[t * 2 + 1];
    f16x8 o;
    o[0] = (f16)(((float)rv[0] - mean) * rstd * g0.x + b0.x);
    o[1] = (f16)(((float)rv[1] - mean) * rstd * g0.y + b0.y);
    o[2] = (f16)(((float)rv[2] - mean) * rstd * g0.z + b0.z);
    o[3] = (f16)(((float)rv[3] - mean) * rstd * g0.w + b0.w);
    o[4] = (f16)(((float)rv[4] - mean) * rstd * g1.x + b1.x);
    o[5] = (f16)(((float)rv[5] - mean) * rstd * g1.y + b1.y);
    o[6] = (f16)(((float)rv[6] - mean) * rstd * g1.z + b1.z);
    o[7] = (f16)(((float)rv[7] - mean) * rstd * g1.w + b1.w);
    ((f16x8*)(out + (size_t)row * DMODEL))[t] = o;
}

// ---------------- final LayerNorm: f16 in -> fp32 h out (own stats) ----------
__global__ __launch_bounds__(256) void lnf_k(const f16* __restrict__ res, const float* __restrict__ g,
                                             const float* __restrict__ b, float* __restrict__ h) {
    int row = blockIdx.x;
    int t = threadIdx.x;
    f16x4 rv = ((const f16x4*)(res + (size_t)row * DMODEL))[t];
    float v0 = (float)rv[0], v1 = (float)rv[1], v2 = (float)rv[2], v3 = (float)rv[3];
    float s = v0 + v1 + v2 + v3;
    float ss = v0 * v0 + v1 * v1 + v2 * v2 + v3 * v3;
    for (int m = 1; m < 64; m <<= 1) { s += __shfl_xor(s, m); ss += __shfl_xor(ss, m); }
    __shared__ float red[8];
    if ((t & 63) == 0) { red[(t >> 6) * 2] = s; red[(t >> 6) * 2 + 1] = ss; }
    __syncthreads();
    s = red[0] + red[2] + red[4] + red[6];
    ss = red[1] + red[3] + red[5] + red[7];
    float mean = s * (1.f / 1024.f);
    float var = ss * (1.f / 1024.f) - mean * mean;
    float rstd = rsqrtf(var + 1e-5f);
    float4 gg = ((const float4*)g)[t];
    float4 bb = ((const float4*)b)[t];
    float4 o;
    o.x = (v0 - mean) * rstd * gg.x + bb.x;
    o.y = (v1 - mean) * rstd * gg.y + bb.y;
    o.z = (v2 - mean) * rstd * gg.z + bb.z;
    o.w = (v3 - mean) * rstd * gg.w + bb.w;
    ((float4*)(h + (size_t)row * DMODEL))[t] = o;
}

// ---------------- mean over S -------------------------------------------------
__global__ __launch_bounds__(256) void pool_k(const float* __restrict__ h, float* __restrict__ pooled) {
    int b = blockIdx.x;
    int t = threadIdx.x;
    float sx = 0, sy = 0, sz = 0, sw = 0;
    for (int s = 0; s < SEQ; ++s) {
        float4 v = ((const float4*)(h + (size_t)(b * SEQ + s) * DMODEL))[t];
        sx += v.x; sy += v.y; sz += v.z; sw += v.w;
    }
    float4 o; o.x = sx * (1.f / 64.f); o.y = sy * (1.f / 64.f); o.z = sz * (1.f / 64.f); o.w = sw * (1.f / 64.f);
    ((float4*)(pooled + (size_t)b * DMODEL))[t] = o;
}

// ---------------- policy / value heads ---------------------------------------
__global__ __launch_bounds__(64) void head_k(const float* __restrict__ pooled, const float* __restrict__ pw,
                                             const float* __restrict__ pb, const float* __restrict__ vw,
                                             const float* __restrict__ vb, float* __restrict__ out) {
    int b = blockIdx.x;
    int lane = threadIdx.x;
    const float* pr = pooled + (size_t)b * DMODEL;
    const float* wr = pw + (size_t)lane * DMODEL;
    float accp = 0.f;
    for (int d = 0; d < DMODEL; d += 4) {
        float4 x = *(const float4*)(pr + d);
        float4 w = *(const float4*)(wr + d);
        accp += x.x * w.x + x.y * w.y + x.z * w.z + x.w * w.w;
    }
    float accv = 0.f;
    for (int d = lane * 4; d < DMODEL; d += 256) {
        float4 x = *(const float4*)(pr + d);
        float4 w = *(const float4*)(vw + d);
        accv += x.x * w.x + x.y * w.y + x.z * w.z + x.w * w.w;
    }
    for (int m = 1; m < 64; m <<= 1) accv += __shfl_xor(accv, m);
    out[b * VOCAB + lane] = accp + pb[lane];
    if (lane == 0) out[BATCH * VOCAB + b] = accv + vb[0];
}

extern "C" void kernel_launch(void* const* d_in, const int* in_sizes, int n_in,
                              void* d_out, int out_size, void* d_ws, size_t ws_size,
                              hipStream_t stream) {
    const int*   x      = (const int*)d_in[0];
    const int*   step   = (const int*)d_in[1];
    const float* tok    = (const float*)d_in[2];
    const float* se     = (const float*)d_in[3];
    const float* qkv_w  = (const float*)d_in[4];
    const float* qkv_b  = (const float*)d_in[5];
    const float* out_w  = (const float*)d_in[6];
    const float* out_b  = (const float*)d_in[7];
    const float* relb   = (const float*)d_in[8];
    const float* w1     = (const float*)d_in[9];
    const float* b1     = (const float*)d_in[10];
    const float* w2     = (const float*)d_in[11];
    const float* b2     = (const float*)d_in[12];
    const float* ln1g   = (const float*)d_in[13];
    const float* ln1b   = (const float*)d_in[14];
    const float* ln2g   = (const float*)d_in[15];
    const float* ln2b   = (const float*)d_in[16];
    const float* lnog   = (const float*)d_in[17];
    const float* lnob   = (const float*)d_in[18];
    const float* pw     = (const float*)d_in[19];
    const float* pb     = (const float*)d_in[20];
    const float* vw     = (const float*)d_in[21];
    const float* vb     = (const float*)d_in[22];

    float* out = (float*)d_out;
    float* h = out + BATCH * VOCAB + BATCH;       // final fp32 h output [16384,1024]

    char* ws = (char*)d_ws;
    f16* rB     = (f16*)(ws);                       // residual (live)      32 MB
    f16* resA   = (f16*)(ws + 33554432);            // residual+delta       32 MB
    f16* qkv16  = (f16*)(ws + 67108864);            // 96 MB
    f16* ctx16  = (f16*)(ws + 167772160);           // 32 MB (inside uni tail)
    f16* ffn16  = (f16*)(ws + 67108864);            // 128 MB (union with qkv+ctx)
    f16* wqb    = (f16*)(ws + 201326592);
    f16* wob    = (f16*)(ws + 207618048);
    f16* w1b    = (f16*)(ws + 209715200);
    f16* w2b    = (f16*)(ws + 218103808);
    float2* part = (float2*)(ws + 226492416);       // [16384][8] = 1 MB
    float* pooled = (float*)(ws + 226492416);       // reuses part (disjoint lifetime)

    embed_k<<<MS, 256, 0, stream>>>(x, step, tok, se, rB);

    for (int l = 0; l < NLAYER; ++l) {
        cvt4_k<<<12288, 256, 0, stream>>>(qkv_w + (size_t)l * 3145728, out_w + (size_t)l * 1048576,
                                          w1 + (size_t)l * 4194304, w2 + (size_t)l * 4194304,
                                          wqb, wob, w1b, w2b);

        gemm_k<0><<<dim3(24, 128), 256, 0, stream>>>(rB, wqb, qkv_b + l * 3072, qkv16,
                                                     nullptr, nullptr, nullptr, MS, 3072, 1024);
        attn_k<<<dim3(NHEAD, BATCH), 64, 0, stream>>>(qkv16, relb + l * 127, ctx16);
        gemm_k<2><<<dim3(8, 128), 256, 0, stream>>>(ctx16, wob, out_b + l * 1024, nullptr,
                                                    rB, resA, part, MS, 1024, 1024);
        ln_k<<<MS, 128, 0, stream>>>(resA, part, ln1g + l * 1024, ln1b + l * 1024, rB);
        gemm_k<1><<<dim3(32, 128), 256, 0, stream>>>(rB, w1b, b1 + l * 4096, ffn16,
                                                     nullptr, nullptr, nullptr, MS, 4096, 1024);
        gemm_k<2><<<dim3(8, 128), 256, 0, stream>>>(ffn16, w2b, b2 + l * 1024, nullptr,
                                                    rB, resA, part, MS, 1024, 4096);
        ln_k<<<MS, 128, 0, stream>>>(resA, part, ln2g + l * 1024, ln2b + l * 1024, rB);
    }

    lnf_k<<<MS, 256, 0, stream>>>(rB, lnog, lnob, h);
    pool_k<<<BATCH, 256, 0, stream>>>(h, pooled);
    head_k<<<BATCH, 64, 0, stream>>>(pooled, pw, pb, vw, vb, out);
}

// Round 8
// 4920.350 us; speedup vs baseline: 1.2719x; 1.0185x over previous
//
#include <hip/hip_runtime.h>
#include <math.h>

typedef _Float16 f16;
typedef _Float16 f16x8 __attribute__((ext_vector_type(8)));
typedef _Float16 f16x4 __attribute__((ext_vector_type(4)));
typedef float floatx4 __attribute__((ext_vector_type(4)));

#define BATCH 256
#define SEQ 64
#define DMODEL 1024
#define NHEAD 16
#define HDIM 64
#define VOCAB 64
#define DFF 4096
#define NLAYER 8
#define MS (BATCH*SEQ)   // 16384 rows

#define GPTR(p) ((const __attribute__((address_space(1))) void*)(p))
#define LPTR(p) ((__attribute__((address_space(3))) void*)(p))

__device__ __forceinline__ floatx4 mfma16(f16x8 a, f16x8 b, floatx4 c) {
    return __builtin_amdgcn_mfma_f32_16x16x32_f16(a, b, c, 0, 0, 0);
}

// fast gelu: x * sigmoid(1.5957691216 * (x + 0.044715 x^3)); max |err| ~3e-4
__device__ __forceinline__ float gelu_f(float x) {
    float x3 = x * x * x;
    float y = -1.5957691216f * fmaf(0.044715f, x3, x);
    return x / (1.f + __expf(y));
}

// ---------------- embed: r = f16(tok[x] + step_embed[step]) -------------------
__global__ __launch_bounds__(256) void embed_k(const int* __restrict__ x, const int* __restrict__ step,
                                               const float* __restrict__ tok, const float* __restrict__ se,
                                               f16* __restrict__ r) {
    int row = blockIdx.x;
    int t = threadIdx.x;
    int id = x[row];
    int si = min(max(step[0], 0), 63);
    float4 a = ((const float4*)(tok + (size_t)id * DMODEL))[t];
    float4 b = ((const float4*)(se + (size_t)si * DMODEL))[t];
    f16x4 hv; hv[0] = (f16)(a.x + b.x); hv[1] = (f16)(a.y + b.y);
    hv[2] = (f16)(a.z + b.z); hv[3] = (f16)(a.w + b.w);
    ((f16x4*)(r + (size_t)row * DMODEL))[t] = hv;
}

// ---------------- fp32 -> f16 convert, all 4 weight mats of a layer ----------
__global__ __launch_bounds__(256) void cvt4_k(const float* __restrict__ qw, const float* __restrict__ ow,
                                              const float* __restrict__ w1, const float* __restrict__ w2,
                                              f16* __restrict__ dq, f16* __restrict__ dO,
                                              f16* __restrict__ d1, f16* __restrict__ d2) {
    int gid = blockIdx.x * 256 + threadIdx.x;   // grid covers 3,145,728 float4s
    const float4* s; f16x4* d; int off;
    if (gid < 786432)        { s = (const float4*)qw; d = (f16x4*)dq; off = gid; }
    else if (gid < 1048576)  { s = (const float4*)ow; d = (f16x4*)dO; off = gid - 786432; }
    else if (gid < 2097152)  { s = (const float4*)w1; d = (f16x4*)d1; off = gid - 1048576; }
    else                     { s = (const float4*)w2; d = (f16x4*)d2; off = gid - 2097152; }
    float4 v = s[off];
    f16x4 o; o[0] = (f16)v.x; o[1] = (f16)v.y; o[2] = (f16)v.z; o[3] = (f16)v.w;
    d[off] = o;
}

// ---------------- GEMM: C[M,N] = A[M,K] @ Bw[N,K]^T --------------------------
// 128x128 tile, BK=64. Asymmetric ring: A 2-deep (2x16KB), B 3-deep (3x16KB)
// = 80 KB LDS -> 2 blocks/CU. Counted vmcnt(4): B(t+2) stays in flight across
// the barrier (weights are the L2-missing operand -> 2-tile latency cover).
// T2 XOR swizzle: physical 16B-block p at row r holds logical p^(r&7).
// 4 waves (2M x 2N), per-wave 64x64 output (acc[4][4]).
// MODE 0: store f16 (bias)   MODE 1: store f16 (bias+gelu)
// MODE 2: res = Rres + acc + bias -> f16 ResOut + per-row partial (sum,sumsq)
template<int MODE>
__global__ __launch_bounds__(256, 2) void gemm_k(const f16* __restrict__ A, const f16* __restrict__ Bw,
                                                 const float* __restrict__ bias,
                                                 f16* __restrict__ Cb,
                                                 const f16* __restrict__ Rres, f16* __restrict__ ResOut,
                                                 float2* __restrict__ Part,
                                                 int M, int N, int K) {
    __shared__ f16 smem[40960];   // A: [2][8192] at 0 ; B: [3][8192] at 16384

    const int tid = threadIdx.x;
    const int lane = tid & 63;
    const int wave = tid >> 6;
    const int wm = wave >> 1, wn = wave & 1;     // 2 x 2 wave grid
    const int lr = lane & 15, lg = lane >> 4;
    const int sa = lr & 7;

    // bijective XCD-aware block swizzle (all grids have nwg % 8 == 0)
    const unsigned nx = gridDim.x;
    const unsigned nwg = nx * gridDim.y;
    unsigned flat = blockIdx.y * nx + blockIdx.x;
    flat = (flat & 7u) * (nwg >> 3) + (flat >> 3);
    const int m0 = (int)(flat / nx) * 128;
    const int n0 = (int)(flat % nx) * 128;

    floatx4 acc[4][4] = {};

    // staging: thread t covers (row = 32c + (t>>3), 16B-block = t&7); pre-swizzled source.
    const int srow = tid >> 3;          // 0..31
    const int scbs = (tid & 7) ^ (srow & 7);
    const f16* Asrc = A + (size_t)(m0 + srow) * K + scbs * 8;
    const f16* Bsrc = Bw + (size_t)(n0 + srow) * K + scbs * 8;
    const int ldsw = wave * 512;        // wave-uniform f16 base (HW adds lane*16B)

#define STAGEA(bi, tt) do {                                                                       \
    const f16* _a = Asrc + (size_t)(tt) * 64;                                                     \
    f16* _l = smem + (bi) * 8192 + ldsw;                                                          \
    __builtin_amdgcn_global_load_lds(GPTR(_a),                  LPTR(_l),        16, 0, 0);       \
    __builtin_amdgcn_global_load_lds(GPTR(_a + 32 * (size_t)K), LPTR(_l + 2048), 16, 0, 0);       \
    __builtin_amdgcn_global_load_lds(GPTR(_a + 64 * (size_t)K), LPTR(_l + 4096), 16, 0, 0);       \
    __builtin_amdgcn_global_load_lds(GPTR(_a + 96 * (size_t)K), LPTR(_l + 6144), 16, 0, 0);       \
} while (0)

#define STAGEB(bi, tt) do {                                                                       \
    const f16* _b = Bsrc + (size_t)(tt) * 64;                                                     \
    f16* _l = smem + 16384 + (bi) * 8192 + ldsw;                                                  \
    __builtin_amdgcn_global_load_lds(GPTR(_b),                  LPTR(_l),        16, 0, 0);       \
    __builtin_amdgcn_global_load_lds(GPTR(_b + 32 * (size_t)K), LPTR(_l + 2048), 16, 0, 0);       \
    __builtin_amdgcn_global_load_lds(GPTR(_b + 64 * (size_t)K), LPTR(_l + 4096), 16, 0, 0);       \
    __builtin_amdgcn_global_load_lds(GPTR(_b + 96 * (size_t)K), LPTR(_l + 6144), 16, 0, 0);       \
} while (0)

    const int NT = K >> 6;   // >= 16 for all our K

    // prologue: A0,B0,B1 in flight (12); need A0,B0 -> vmcnt(4)
    STAGEA(0, 0);
    STAGEB(0, 0);
    STAGEB(1, 1);
    asm volatile("s_waitcnt vmcnt(4)" ::: "memory");
    __builtin_amdgcn_s_barrier();

    int ab = 0, bb = 0;
    for (int t = 0; t < NT; ++t) {
        // issue next stages: A 1-ahead (into ab^1, holds A(t-1), fully read),
        // B 2-ahead (into (bb+2)%3, holds B(t-1), fully read).
        if (t + 1 < NT) STAGEA(ab ^ 1, t + 1);
        if (t + 2 < NT) { int b2 = bb + 2; if (b2 >= 3) b2 -= 3; STAGEB(b2, t + 2); }

        const f16* Ab = smem + ab * 8192;
        const f16* Bb = smem + 16384 + bb * 8192;
        f16x8 af[8], bf[8];
#pragma unroll
        for (int kh = 0; kh < 2; ++kh)
#pragma unroll
            for (int mi = 0; mi < 4; ++mi)
                af[kh * 4 + mi] = *(const f16x8*)(Ab + (wm * 64 + mi * 16 + lr) * 64
                                                  + (((kh * 4 + lg) ^ sa) << 3));
#pragma unroll
        for (int kh = 0; kh < 2; ++kh)
#pragma unroll
            for (int ni = 0; ni < 4; ++ni)
                bf[kh * 4 + ni] = *(const f16x8*)(Bb + (wn * 64 + ni * 16 + lr) * 64
                                                  + (((kh * 4 + lg) ^ sa) << 3));

        __builtin_amdgcn_s_setprio(1);
#pragma unroll
        for (int kh = 0; kh < 2; ++kh)
#pragma unroll
            for (int mi = 0; mi < 4; ++mi)
#pragma unroll
                for (int ni = 0; ni < 4; ++ni)
                    acc[mi][ni] = mfma16(af[kh * 4 + mi], bf[kh * 4 + ni], acc[mi][ni]);
        __builtin_amdgcn_s_setprio(0);

        // buffer-ready for t+1: oldest 8 outstanding are B(t+1),A(t+1);
        // B(t+2)'s 4 may stay in flight (counted, never drain mid-loop).
        if (t + 2 < NT)      { asm volatile("s_waitcnt vmcnt(4)" ::: "memory"); }
        else if (t + 1 < NT) { asm volatile("s_waitcnt vmcnt(0)" ::: "memory"); }
        __builtin_amdgcn_s_barrier();

        ab ^= 1;
        bb = (bb == 2) ? 0 : bb + 1;
    }
#undef STAGEA
#undef STAGEB

    if (MODE == 2) {
        float bsv[4];
#pragma unroll
        for (int ni = 0; ni < 4; ++ni) bsv[ni] = bias[n0 + wn * 64 + ni * 16 + lr];
        f16* scr = smem + wave * 4096;      // A region (free after loop)
#pragma unroll
        for (int mi = 0; mi < 4; ++mi)
#pragma unroll
            for (int ni = 0; ni < 4; ++ni)
#pragma unroll
                for (int j = 0; j < 4; ++j) {
                    int rr = mi * 16 + lg * 4 + j;
                    int cc = ni * 16 + lr;
                    scr[rr * 64 + (((cc >> 3) ^ (rr & 7)) * 8) + (cc & 7)]
                        = (f16)(acc[mi][ni][j] + bsv[ni]);
                }
        int gr = m0 + wm * 64 + lane;
        const f16* rrow = Rres + (size_t)gr * N + n0 + wn * 64;
        f16* orow = ResOut + (size_t)gr * N + n0 + wn * 64;
        float s = 0.f, ss = 0.f;
#pragma unroll
        for (int i = 0; i < 8; ++i) {
            f16x8 a = *(const f16x8*)(scr + lane * 64 + ((i ^ (lane & 7)) * 8));
            f16x8 rv = *(const f16x8*)(rrow + i * 8);
            f16x8 o;
#pragma unroll
            for (int k = 0; k < 8; ++k) {
                float v = (float)a[k] + (float)rv[k];
                s += v; ss += v * v;
                o[k] = (f16)v;
            }
            *(f16x8*)(orow + i * 8) = o;
        }
        float* red = (float*)(smem + 16384);   // B region (free after loop)
        if (wn == 1) { red[(wm * 64 + lane) * 2] = s; red[(wm * 64 + lane) * 2 + 1] = ss; }
        __syncthreads();
        if (wn == 0) {
            float s2 = red[(wm * 64 + lane) * 2], ss2 = red[(wm * 64 + lane) * 2 + 1];
            Part[(size_t)gr * (N >> 7) + (n0 >> 7)] = float2{s + s2, ss + ss2};
        }
    } else {
        f16* scr = smem + wave * 4096;
        float bsv[4];
#pragma unroll
        for (int ni = 0; ni < 4; ++ni) bsv[ni] = bias[n0 + wn * 64 + ni * 16 + lr];
#pragma unroll
        for (int mi = 0; mi < 4; ++mi)
#pragma unroll
            for (int ni = 0; ni < 4; ++ni)
#pragma unroll
                for (int j = 0; j < 4; ++j) {
                    int rr = mi * 16 + lg * 4 + j;
                    int cc = ni * 16 + lr;
                    float v = acc[mi][ni][j] + bsv[ni];
                    if (MODE == 1) v = gelu_f(v);
                    scr[rr * 64 + (((cc >> 3) ^ (rr & 7)) * 8) + (cc & 7)] = (f16)v;
                }
        int gr = m0 + wm * 64 + lane;
        f16* dst = Cb + (size_t)gr * N + n0 + wn * 64;
#pragma unroll
        for (int i = 0; i < 8; ++i) {
            f16x8 v = *(const f16x8*)(scr + lane * 64 + ((i ^ (lane & 7)) * 8));
            *(f16x8*)(dst + i * 8) = v;
        }
    }
}

// ---------------- attention: one wave per (b,h) -------------------------------
__global__ __launch_bounds__(64) void attn_k(const f16* __restrict__ qkv, const float* __restrict__ rb,
                                             f16* __restrict__ ctx) {
    const int hh = blockIdx.x;
    const int bb = blockIdx.y;
    const int lane = threadIdx.x;
    __shared__ float rbs[128];
    __shared__ f16 Vt[64][72];
    __shared__ f16 Pl[64][72];

    for (int i = lane; i < 127; i += 64) rbs[i] = rb[i];

    const f16* vrow = qkv + (size_t)(bb * 64 + lane) * 3072 + 2048 + hh * 64;
#pragma unroll
    for (int i = 0; i < 8; ++i) {
        f16x8 v = *(const f16x8*)(vrow + i * 8);
#pragma unroll
        for (int j = 0; j < 8; ++j) Vt[i * 8 + j][lane] = v[j];
    }
    __syncthreads();

    const int lr = lane & 15, lg = lane >> 4;
    floatx4 sacc[4][4] = {};
    const f16* qbase = qkv + (size_t)(bb * 64) * 3072 + hh * 64;
#pragma unroll
    for (int kk = 0; kk < 64; kk += 32) {
        f16x8 qa[4], kb[4];
#pragma unroll
        for (int mf = 0; mf < 4; ++mf)
            qa[mf] = *(const f16x8*)(qbase + (size_t)(mf * 16 + lr) * 3072 + kk + lg * 8);
#pragma unroll
        for (int nf = 0; nf < 4; ++nf)
            kb[nf] = *(const f16x8*)(qbase + 1024 + (size_t)(nf * 16 + lr) * 3072 + kk + lg * 8);
#pragma unroll
        for (int mf = 0; mf < 4; ++mf)
#pragma unroll
            for (int nf = 0; nf < 4; ++nf)
                sacc[mf][nf] = mfma16(qa[mf], kb[nf], sacc[mf][nf]);
    }

#pragma unroll
    for (int mf = 0; mf < 4; ++mf) {
#pragma unroll
        for (int j = 0; j < 4; ++j) {
            int qrow = mf * 16 + lg * 4 + j;
            float v0 = sacc[mf][0][j] * 0.125f + rbs[qrow - (0  + lr) + 63];
            float v1 = sacc[mf][1][j] * 0.125f + rbs[qrow - (16 + lr) + 63];
            float v2 = sacc[mf][2][j] * 0.125f + rbs[qrow - (32 + lr) + 63];
            float v3 = sacc[mf][3][j] * 0.125f + rbs[qrow - (48 + lr) + 63];
            float mx = fmaxf(fmaxf(v0, v1), fmaxf(v2, v3));
            for (int m = 1; m < 16; m <<= 1) mx = fmaxf(mx, __shfl_xor(mx, m));
            v0 = __expf(v0 - mx); v1 = __expf(v1 - mx); v2 = __expf(v2 - mx); v3 = __expf(v3 - mx);
            float sum = v0 + v1 + v2 + v3;
            for (int m = 1; m < 16; m <<= 1) sum += __shfl_xor(sum, m);
            float inv = 1.f / sum;
            Pl[qrow][0  + lr] = (f16)(v0 * inv);
            Pl[qrow][16 + lr] = (f16)(v1 * inv);
            Pl[qrow][32 + lr] = (f16)(v2 * inv);
            Pl[qrow][48 + lr] = (f16)(v3 * inv);
        }
    }
    __syncthreads();

    floatx4 oacc[4][4] = {};
#pragma unroll
    for (int kk = 0; kk < 64; kk += 32) {
        f16x8 pa[4], vb[4];
#pragma unroll
        for (int mf = 0; mf < 4; ++mf) pa[mf] = *(const f16x8*)&Pl[mf * 16 + lr][kk + lg * 8];
#pragma unroll
        for (int nf = 0; nf < 4; ++nf) vb[nf] = *(const f16x8*)&Vt[nf * 16 + lr][kk + lg * 8];
#pragma unroll
        for (int mf = 0; mf < 4; ++mf)
#pragma unroll
            for (int nf = 0; nf < 4; ++nf)
                oacc[mf][nf] = mfma16(pa[mf], vb[nf], oacc[mf][nf]);
    }
    __syncthreads();
#pragma unroll
    for (int mf = 0; mf < 4; ++mf)
#pragma unroll
        for (int nf = 0; nf < 4; ++nf)
#pragma unroll
            for (int j = 0; j < 4; ++j)
                Pl[mf * 16 + lg * 4 + j][nf * 16 + lr] = (f16)oacc[mf][nf][j];
    __syncthreads();
    f16* crow = ctx + (size_t)(bb * 64 + lane) * DMODEL + hh * 64;
#pragma unroll
    for (int i = 0; i < 8; ++i) {
        f16x8 v = *(const f16x8*)&Pl[lane][i * 8];
        *(f16x8*)(crow + i * 8) = v;
    }
}

// ---------------- LayerNorm from fused partials: out = LN(res) (f16) ---------
__global__ __launch_bounds__(128) void ln_k(const f16* __restrict__ res, const float2* __restrict__ part,
                                            const float* __restrict__ g, const float* __restrict__ b,
                                            f16* __restrict__ out) {
    int row = blockIdx.x;
    int t = threadIdx.x;
    f16x8 rv = ((const f16x8*)(res + (size_t)row * DMODEL))[t];
    float s = 0.f, ss = 0.f;
#pragma unroll
    for (int c = 0; c < 8; ++c) {
        float2 p = part[(size_t)row * 8 + c];
        s += p.x; ss += p.y;
    }
    float mean = s * (1.f / 1024.f);
    float var = ss * (1.f / 1024.f) - mean * mean;
    float rstd = rsqrtf(var + 1e-5f);
    float4 g0 = ((const float4*)g)[t * 2], g1 = ((const float4*)g)[t * 2 + 1];
    float4 b0 = ((const float4*)b)[t * 2], b1 = ((const float4*)b)[t * 2 + 1];
    f16x8 o;
    o[0] = (f16)(((float)rv[0] - mean) * rstd * g0.x + b0.x);
    o[1] = (f16)(((float)rv[1] - mean) * rstd * g0.y + b0.y);
    o[2] = (f16)(((float)rv[2] - mean) * rstd * g0.z + b0.z);
    o[3] = (f16)(((float)rv[3] - mean) * rstd * g0.w + b0.w);
    o[4] = (f16)(((float)rv[4] - mean) * rstd * g1.x + b1.x);
    o[5] = (f16)(((float)rv[5] - mean) * rstd * g1.y + b1.y);
    o[6] = (f16)(((float)rv[6] - mean) * rstd * g1.z + b1.z);
    o[7] = (f16)(((float)rv[7] - mean) * rstd * g1.w + b1.w);
    ((f16x8*)(out + (size_t)row * DMODEL))[t] = o;
}

// ---------------- final LayerNorm: f16 in -> fp32 h out (own stats) ----------
__global__ __launch_bounds__(256) void lnf_k(const f16* __restrict__ res, const float* __restrict__ g,
                                             const float* __restrict__ b, float* __restrict__ h) {
    int row = blockIdx.x;
    int t = threadIdx.x;
    f16x4 rv = ((const f16x4*)(res + (size_t)row * DMODEL))[t];
    float v0 = (float)rv[0], v1 = (float)rv[1], v2 = (float)rv[2], v3 = (float)rv[3];
    float s = v0 + v1 + v2 + v3;
    float ss = v0 * v0 + v1 * v1 + v2 * v2 + v3 * v3;
    for (int m = 1; m < 64; m <<= 1) { s += __shfl_xor(s, m); ss += __shfl_xor(ss, m); }
    __shared__ float red[8];
    if ((t & 63) == 0) { red[(t >> 6) * 2] = s; red[(t >> 6) * 2 + 1] = ss; }
    __syncthreads();
    s = red[0] + red[2] + red[4] + red[6];
    ss = red[1] + red[3] + red[5] + red[7];
    float mean = s * (1.f / 1024.f);
    float var = ss * (1.f / 1024.f) - mean * mean;
    float rstd = rsqrtf(var + 1e-5f);
    float4 gg = ((const float4*)g)[t];
    float4 bb = ((const float4*)b)[t];
    float4 o;
    o.x = (v0 - mean) * rstd * gg.x + bb.x;
    o.y = (v1 - mean) * rstd * gg.y + bb.y;
    o.z = (v2 - mean) * rstd * gg.z + bb.z;
    o.w = (v3 - mean) * rstd * gg.w + bb.w;
    ((float4*)(h + (size_t)row * DMODEL))[t] = o;
}

// ---------------- mean over S -------------------------------------------------
__global__ __launch_bounds__(256) void pool_k(const float* __restrict__ h, float* __restrict__ pooled) {
    int b = blockIdx.x;
    int t = threadIdx.x;
    float sx = 0, sy = 0, sz = 0, sw = 0;
    for (int s = 0; s < SEQ; ++s) {
        float4 v = ((const float4*)(h + (size_t)(b * SEQ + s) * DMODEL))[t];
        sx += v.x; sy += v.y; sz += v.z; sw += v.w;
    }
    float4 o; o.x = sx * (1.f / 64.f); o.y = sy * (1.f / 64.f); o.z = sz * (1.f / 64.f); o.w = sw * (1.f / 64.f);
    ((float4*)(pooled + (size_t)b * DMODEL))[t] = o;
}

// ---------------- policy / value heads ---------------------------------------
__global__ __launch_bounds__(64) void head_k(const float* __restrict__ pooled, const float* __restrict__ pw,
                                             const float* __restrict__ pb, const float* __restrict__ vw,
                                             const float* __restrict__ vb, float* __restrict__ out) {
    int b = blockIdx.x;
    int lane = threadIdx.x;
    const float* pr = pooled + (size_t)b * DMODEL;
    const float* wr = pw + (size_t)lane * DMODEL;
    float accp = 0.f;
    for (int d = 0; d < DMODEL; d += 4) {
        float4 x = *(const float4*)(pr + d);
        float4 w = *(const float4*)(wr + d);
        accp += x.x * w.x + x.y * w.y + x.z * w.z + x.w * w.w;
    }
    float accv = 0.f;
    for (int d = lane * 4; d < DMODEL; d += 256) {
        float4 x = *(const float4*)(pr + d);
        float4 w = *(const float4*)(vw + d);
        accv += x.x * w.x + x.y * w.y + x.z * w.z + x.w * w.w;
    }
    for (int m = 1; m < 64; m <<= 1) accv += __shfl_xor(accv, m);
    out[b * VOCAB + lane] = accp + pb[lane];
    if (lane == 0) out[BATCH * VOCAB + b] = accv + vb[0];
}

extern "C" void kernel_launch(void* const* d_in, const int* in_sizes, int n_in,
                              void* d_out, int out_size, void* d_ws, size_t ws_size,
                              hipStream_t stream) {
    const int*   x      = (const int*)d_in[0];
    const int*   step   = (const int*)d_in[1];
    const float* tok    = (const float*)d_in[2];
    const float* se     = (const float*)d_in[3];
    const float* qkv_w  = (const float*)d_in[4];
    const float* qkv_b  = (const float*)d_in[5];
    const float* out_w  = (const float*)d_in[6];
    const float* out_b  = (const float*)d_in[7];
    const float* relb   = (const float*)d_in[8];
    const float* w1     = (const float*)d_in[9];
    const float* b1     = (const float*)d_in[10];
    const float* w2     = (const float*)d_in[11];
    const float* b2     = (const float*)d_in[12];
    const float* ln1g   = (const float*)d_in[13];
    const float* ln1b   = (const float*)d_in[14];
    const float* ln2g   = (const float*)d_in[15];
    const float* ln2b   = (const float*)d_in[16];
    const float* lnog   = (const float*)d_in[17];
    const float* lnob   = (const float*)d_in[18];
    const float* pw     = (const float*)d_in[19];
    const float* pb     = (const float*)d_in[20];
    const float* vw     = (const float*)d_in[21];
    const float* vb     = (const float*)d_in[22];

    float* out = (float*)d_out;
    float* h = out + BATCH * VOCAB + BATCH;       // final fp32 h output [16384,1024]

    char* ws = (char*)d_ws;
    f16* rB     = (f16*)(ws);                       // residual (live)      32 MB
    f16* resA   = (f16*)(ws + 33554432);            // residual+delta       32 MB
    f16* qkv16  = (f16*)(ws + 67108864);            // 96 MB
    f16* ctx16  = (f16*)(ws + 167772160);           // 32 MB
    f16* ffn16  = (f16*)(ws + 67108864);            // 128 MB (union with qkv+ctx)
    f16* wqb    = (f16*)(ws + 201326592);
    f16* wob    = (f16*)(ws + 207618048);
    f16* w1b    = (f16*)(ws + 209715200);
    f16* w2b    = (f16*)(ws + 218103808);
    float2* part = (float2*)(ws + 226492416);       // [16384][8] = 1 MB
    float* pooled = (float*)(ws + 226492416);       // reuses part (disjoint lifetime)

    embed_k<<<MS, 256, 0, stream>>>(x, step, tok, se, rB);

    for (int l = 0; l < NLAYER; ++l) {
        cvt4_k<<<12288, 256, 0, stream>>>(qkv_w + (size_t)l * 3145728, out_w + (size_t)l * 1048576,
                                          w1 + (size_t)l * 4194304, w2 + (size_t)l * 4194304,
                                          wqb, wob, w1b, w2b);

        gemm_k<0><<<dim3(24, 128), 256, 0, stream>>>(rB, wqb, qkv_b + l * 3072, qkv16,
                                                     nullptr, nullptr, nullptr, MS, 3072, 1024);
        attn_k<<<dim3(NHEAD, BATCH), 64, 0, stream>>>(qkv16, relb + l * 127, ctx16);
        gemm_k<2><<<dim3(8, 128), 256, 0, stream>>>(ctx16, wob, out_b + l * 1024, nullptr,
                                                    rB, resA, part, MS, 1024, 1024);
        ln_k<<<MS, 128, 0, stream>>>(resA, part, ln1g + l * 1024, ln1b + l * 1024, rB);
        gemm_k<1><<<dim3(32, 128), 256, 0, stream>>>(rB, w1b, b1 + l * 4096, ffn16,
                                                     nullptr, nullptr, nullptr, MS, 4096, 1024);
        gemm_k<2><<<dim3(8, 128), 256, 0, stream>>>(ffn16, w2b, b2 + l * 1024, nullptr,
                                                    rB, resA, part, MS, 1024, 4096);
        ln_k<<<MS, 128, 0, stream>>>(resA, part, ln2g + l * 1024, ln2b + l * 1024, rB);
    }

    lnf_k<<<MS, 256, 0, stream>>>(rB, lnog, lnob, h);
    pool_k<<<BATCH, 256, 0, stream>>>(h, pooled);
    head_k<<<BATCH, 64, 0, stream>>>(pooled, pw, pb, vw, vb, out);
}

// Round 9
// 4859.853 us; speedup vs baseline: 1.2877x; 1.0124x over previous
//
#include <hip/hip_runtime.h>
#include <math.h>

typedef _Float16 f16;
typedef _Float16 f16x8 __attribute__((ext_vector_type(8)));
typedef _Float16 f16x4 __attribute__((ext_vector_type(4)));
typedef float floatx4 __attribute__((ext_vector_type(4)));

#define BATCH 256
#define SEQ 64
#define DMODEL 1024
#define NHEAD 16
#define HDIM 64
#define VOCAB 64
#define DFF 4096
#define NLAYER 8
#define MS (BATCH*SEQ)   // 16384 rows

#define GPTR(p) ((const __attribute__((address_space(1))) void*)(p))
#define LPTR(p) ((__attribute__((address_space(3))) void*)(p))

__device__ __forceinline__ floatx4 mfma16(f16x8 a, f16x8 b, floatx4 c) {
    return __builtin_amdgcn_mfma_f32_16x16x32_f16(a, b, c, 0, 0, 0);
}

// fast gelu: x * sigmoid(1.5957691216 * (x + 0.044715 x^3)); max |err| ~3e-4
__device__ __forceinline__ float gelu_f(float x) {
    float x3 = x * x * x;
    float y = -1.5957691216f * fmaf(0.044715f, x3, x);
    return x / (1.f + __expf(y));
}

// ---------------- embed: r = f16(tok[x] + step_embed[step]) -------------------
__global__ __launch_bounds__(256) void embed_k(const int* __restrict__ x, const int* __restrict__ step,
                                               const float* __restrict__ tok, const float* __restrict__ se,
                                               f16* __restrict__ r) {
    int row = blockIdx.x;
    int t = threadIdx.x;
    int id = x[row];
    int si = min(max(step[0], 0), 63);
    float4 a = ((const float4*)(tok + (size_t)id * DMODEL))[t];
    float4 b = ((const float4*)(se + (size_t)si * DMODEL))[t];
    f16x4 hv; hv[0] = (f16)(a.x + b.x); hv[1] = (f16)(a.y + b.y);
    hv[2] = (f16)(a.z + b.z); hv[3] = (f16)(a.w + b.w);
    ((f16x4*)(r + (size_t)row * DMODEL))[t] = hv;
}

// ---------------- fp32 -> f16 convert, all 4 weight mats of a layer ----------
__global__ __launch_bounds__(256) void cvt4_k(const float* __restrict__ qw, const float* __restrict__ ow,
                                              const float* __restrict__ w1, const float* __restrict__ w2,
                                              f16* __restrict__ dq, f16* __restrict__ dO,
                                              f16* __restrict__ d1, f16* __restrict__ d2) {
    int gid = blockIdx.x * 256 + threadIdx.x;   // grid covers 3,145,728 float4s
    const float4* s; f16x4* d; int off;
    if (gid < 786432)        { s = (const float4*)qw; d = (f16x4*)dq; off = gid; }
    else if (gid < 1048576)  { s = (const float4*)ow; d = (f16x4*)dO; off = gid - 786432; }
    else if (gid < 2097152)  { s = (const float4*)w1; d = (f16x4*)d1; off = gid - 1048576; }
    else                     { s = (const float4*)w2; d = (f16x4*)d2; off = gid - 2097152; }
    float4 v = s[off];
    f16x4 o; o[0] = (f16)v.x; o[1] = (f16)v.y; o[2] = (f16)v.z; o[3] = (f16)v.w;
    d[off] = o;
}

// ---------------- GEMM: C[M,N] = A[M,K] @ Bw[N,K]^T --------------------------
// 256x128 block tile, BK=32, ring-of-3 (A+B together, 3x24KB = 72KB) -> 2 blk/CU.
// Counted vmcnt(6): 2-tile prefetch, 1 barrier/tile. 4 waves (2M x 2N),
// per-wave 128x64 output (acc[8][4]) -> 33% better FLOP per LDS byte.
// Swizzle (BK=32): phys 16B-blk p at row r holds logical p ^ s(r), s(r)=((r^(r>>2))&3).
// MODE 0: store f16 (bias)   MODE 1: store f16 (bias+gelu)
// MODE 2: res = Rres + acc + bias -> f16 ResOut + per-row partial (sum,sumsq)
template<int MODE>
__global__ __launch_bounds__(256, 2) void gemm_k(const f16* __restrict__ A, const f16* __restrict__ Bw,
                                                 const float* __restrict__ bias,
                                                 f16* __restrict__ Cb,
                                                 const f16* __restrict__ Rres, f16* __restrict__ ResOut,
                                                 float2* __restrict__ Part,
                                                 int M, int N, int K) {
    __shared__ f16 smem[36864];   // 3 bufs x (A 256x32 | B 128x32) f16 = 72 KB

    const int tid = threadIdx.x;
    const int lane = tid & 63;
    const int wave = tid >> 6;
    const int wm = wave >> 1, wn = wave & 1;     // 2 x 2 wave grid
    const int lr = lane & 15, lg = lane >> 4;
    const int sa = (lr ^ (lr >> 2)) & 3;

    // bijective XCD-aware block swizzle (all grids have nwg % 8 == 0)
    const unsigned nx = gridDim.x;
    const unsigned nwg = nx * gridDim.y;
    unsigned flat = blockIdx.y * nx + blockIdx.x;
    flat = (flat & 7u) * (nwg >> 3) + (flat >> 3);
    const int m0 = (int)(flat / nx) * 256;
    const int n0 = (int)(flat % nx) * 128;

    floatx4 acc[8][4] = {};

    // staging: thread t covers (row = 64c + (t>>2), 16B-block = t&3); pre-swizzled src.
    const int srow = tid >> 2;          // 0..63
    const int lblk = (tid & 3) ^ ((srow ^ (srow >> 2)) & 3);
    const f16* AsrcT = A + (size_t)(m0 + srow) * K + lblk * 8;
    const f16* BsrcT = Bw + (size_t)(n0 + srow) * K + lblk * 8;
    const int ldsw = wave * 512;        // wave-uniform f16 base (HW adds lane*16B)

#define STAGE(bi, tt) do {                                                                        \
    const f16* _a = AsrcT + (size_t)(tt) * 32;                                                    \
    const f16* _b = BsrcT + (size_t)(tt) * 32;                                                    \
    f16* _l = smem + (bi) * 12288 + ldsw;                                                         \
    __builtin_amdgcn_global_load_lds(GPTR(_a),                   LPTR(_l),         16, 0, 0);     \
    __builtin_amdgcn_global_load_lds(GPTR(_a +  64 * (size_t)K), LPTR(_l + 2048),  16, 0, 0);     \
    __builtin_amdgcn_global_load_lds(GPTR(_a + 128 * (size_t)K), LPTR(_l + 4096),  16, 0, 0);     \
    __builtin_amdgcn_global_load_lds(GPTR(_a + 192 * (size_t)K), LPTR(_l + 6144),  16, 0, 0);     \
    __builtin_amdgcn_global_load_lds(GPTR(_b),                   LPTR(_l + 8192),  16, 0, 0);     \
    __builtin_amdgcn_global_load_lds(GPTR(_b +  64 * (size_t)K), LPTR(_l + 10240), 16, 0, 0);     \
} while (0)

    const int NT = K >> 5;   // >= 32 for all our K

    STAGE(0, 0);
    STAGE(1, 1);

    int buf = 0;
    for (int t = 0; t < NT; ++t) {
        // tile t's 6 loads are the oldest outstanding; t+1's 6 stay in flight.
        if (t + 1 < NT) { asm volatile("s_waitcnt vmcnt(6)" ::: "memory"); }
        else            { asm volatile("s_waitcnt vmcnt(0)" ::: "memory"); }
        __builtin_amdgcn_s_barrier();

        // stage t+2 into buf (t+2)%3 (holds tile t-1, fully consumed pre-barrier)
        if (t + 2 < NT) { int st = buf >= 1 ? buf - 1 : 2; STAGE(st, t + 2); }

        const f16* Ab = smem + buf * 12288;
        const f16* Bb = Ab + 8192;
        f16x8 af[8], bf[4];
#pragma unroll
        for (int ni = 0; ni < 4; ++ni)
            bf[ni] = *(const f16x8*)(Bb + (wn * 64 + ni * 16 + lr) * 32 + ((lg ^ sa) << 3));
#pragma unroll
        for (int mi = 0; mi < 8; ++mi)
            af[mi] = *(const f16x8*)(Ab + (wm * 128 + mi * 16 + lr) * 32 + ((lg ^ sa) << 3));

        __builtin_amdgcn_s_setprio(1);
#pragma unroll
        for (int mi = 0; mi < 8; ++mi)
#pragma unroll
            for (int ni = 0; ni < 4; ++ni)
                acc[mi][ni] = mfma16(af[mi], bf[ni], acc[mi][ni]);
        __builtin_amdgcn_s_setprio(0);

        buf = (buf == 2) ? 0 : buf + 1;
    }
#undef STAGE

    if (MODE == 2) {
        float bsv[4];
#pragma unroll
        for (int ni = 0; ni < 4; ++ni) bsv[ni] = bias[n0 + wn * 64 + ni * 16 + lr];
        f16* scr = smem + wave * 8192;      // wave-private 128x64 f16
#pragma unroll
        for (int mi = 0; mi < 8; ++mi)
#pragma unroll
            for (int ni = 0; ni < 4; ++ni)
#pragma unroll
                for (int j = 0; j < 4; ++j) {
                    int rr = mi * 16 + lg * 4 + j;
                    int cc = ni * 16 + lr;
                    scr[rr * 64 + (((cc >> 3) ^ (rr & 7)) * 8) + (cc & 7)]
                        = (f16)(acc[mi][ni][j] + bsv[ni]);
                }
        float2* red = (float2*)(smem + 32768);   // byte 65536.. (4 KB, free region)
#pragma unroll
        for (int half = 0; half < 2; ++half) {
            int r2 = half * 64 + lane;
            int gr = m0 + wm * 128 + r2;
            const f16* rrow = Rres + (size_t)gr * N + n0 + wn * 64;
            f16* orow = ResOut + (size_t)gr * N + n0 + wn * 64;
            float s = 0.f, ss = 0.f;
#pragma unroll
            for (int i = 0; i < 8; ++i) {
                f16x8 a = *(const f16x8*)(scr + r2 * 64 + ((i ^ (r2 & 7)) * 8));
                f16x8 rv = *(const f16x8*)(rrow + i * 8);
                f16x8 o;
#pragma unroll
                for (int k = 0; k < 8; ++k) {
                    float v = (float)a[k] + (float)rv[k];
                    s += v; ss += v * v;
                    o[k] = (f16)v;
                }
                *(f16x8*)(orow + i * 8) = o;
            }
            red[((wm * 128 + r2) << 1) | wn] = float2{s, ss};
        }
        __syncthreads();
        if (wn == 0) {
#pragma unroll
            for (int half = 0; half < 2; ++half) {
                int row = wm * 128 + half * 64 + lane;
                int gr = m0 + row;
                float2 p0 = red[row << 1], p1 = red[(row << 1) | 1];
                Part[(size_t)gr * (N >> 7) + (n0 >> 7)] = float2{p0.x + p1.x, p0.y + p1.y};
            }
        }
    } else {
        f16* scr = smem + wave * 8192;      // wave-private 128x64 f16 (no barriers)
        float bsv[4];
#pragma unroll
        for (int ni = 0; ni < 4; ++ni) bsv[ni] = bias[n0 + wn * 64 + ni * 16 + lr];
#pragma unroll
        for (int mi = 0; mi < 8; ++mi)
#pragma unroll
            for (int ni = 0; ni < 4; ++ni)
#pragma unroll
                for (int j = 0; j < 4; ++j) {
                    int rr = mi * 16 + lg * 4 + j;
                    int cc = ni * 16 + lr;
                    float v = acc[mi][ni][j] + bsv[ni];
                    if (MODE == 1) v = gelu_f(v);
                    scr[rr * 64 + (((cc >> 3) ^ (rr & 7)) * 8) + (cc & 7)] = (f16)v;
                }
#pragma unroll
        for (int half = 0; half < 2; ++half) {
            int r2 = half * 64 + lane;
            int gr = m0 + wm * 128 + r2;
            f16* dst = Cb + (size_t)gr * N + n0 + wn * 64;
#pragma unroll
            for (int i = 0; i < 8; ++i) {
                f16x8 v = *(const f16x8*)(scr + r2 * 64 + ((i ^ (r2 & 7)) * 8));
                *(f16x8*)(dst + i * 8) = v;
            }
        }
    }
}

// ---------------- attention: one wave per (b,h) -------------------------------
__global__ __launch_bounds__(64) void attn_k(const f16* __restrict__ qkv, const float* __restrict__ rb,
                                             f16* __restrict__ ctx) {
    const int hh = blockIdx.x;
    const int bb = blockIdx.y;
    const int lane = threadIdx.x;
    __shared__ float rbs[128];
    __shared__ f16 Vt[64][72];
    __shared__ f16 Pl[64][72];

    for (int i = lane; i < 127; i += 64) rbs[i] = rb[i];

    const f16* vrow = qkv + (size_t)(bb * 64 + lane) * 3072 + 2048 + hh * 64;
#pragma unroll
    for (int i = 0; i < 8; ++i) {
        f16x8 v = *(const f16x8*)(vrow + i * 8);
#pragma unroll
        for (int j = 0; j < 8; ++j) Vt[i * 8 + j][lane] = v[j];
    }
    __syncthreads();

    const int lr = lane & 15, lg = lane >> 4;
    floatx4 sacc[4][4] = {};
    const f16* qbase = qkv + (size_t)(bb * 64) * 3072 + hh * 64;
#pragma unroll
    for (int kk = 0; kk < 64; kk += 32) {
        f16x8 qa[4], kb[4];
#pragma unroll
        for (int mf = 0; mf < 4; ++mf)
            qa[mf] = *(const f16x8*)(qbase + (size_t)(mf * 16 + lr) * 3072 + kk + lg * 8);
#pragma unroll
        for (int nf = 0; nf < 4; ++nf)
            kb[nf] = *(const f16x8*)(qbase + 1024 + (size_t)(nf * 16 + lr) * 3072 + kk + lg * 8);
#pragma unroll
        for (int mf = 0; mf < 4; ++mf)
#pragma unroll
            for (int nf = 0; nf < 4; ++nf)
                sacc[mf][nf] = mfma16(qa[mf], kb[nf], sacc[mf][nf]);
    }

#pragma unroll
    for (int mf = 0; mf < 4; ++mf) {
#pragma unroll
        for (int j = 0; j < 4; ++j) {
            int qrow = mf * 16 + lg * 4 + j;
            float v0 = sacc[mf][0][j] * 0.125f + rbs[qrow - (0  + lr) + 63];
            float v1 = sacc[mf][1][j] * 0.125f + rbs[qrow - (16 + lr) + 63];
            float v2 = sacc[mf][2][j] * 0.125f + rbs[qrow - (32 + lr) + 63];
            float v3 = sacc[mf][3][j] * 0.125f + rbs[qrow - (48 + lr) + 63];
            float mx = fmaxf(fmaxf(v0, v1), fmaxf(v2, v3));
            for (int m = 1; m < 16; m <<= 1) mx = fmaxf(mx, __shfl_xor(mx, m));
            v0 = __expf(v0 - mx); v1 = __expf(v1 - mx); v2 = __expf(v2 - mx); v3 = __expf(v3 - mx);
            float sum = v0 + v1 + v2 + v3;
            for (int m = 1; m < 16; m <<= 1) sum += __shfl_xor(sum, m);
            float inv = 1.f / sum;
            Pl[qrow][0  + lr] = (f16)(v0 * inv);
            Pl[qrow][16 + lr] = (f16)(v1 * inv);
            Pl[qrow][32 + lr] = (f16)(v2 * inv);
            Pl[qrow][48 + lr] = (f16)(v3 * inv);
        }
    }
    __syncthreads();

    floatx4 oacc[4][4] = {};
#pragma unroll
    for (int kk = 0; kk < 64; kk += 32) {
        f16x8 pa[4], vb[4];
#pragma unroll
        for (int mf = 0; mf < 4; ++mf) pa[mf] = *(const f16x8*)&Pl[mf * 16 + lr][kk + lg * 8];
#pragma unroll
        for (int nf = 0; nf < 4; ++nf) vb[nf] = *(const f16x8*)&Vt[nf * 16 + lr][kk + lg * 8];
#pragma unroll
        for (int mf = 0; mf < 4; ++mf)
#pragma unroll
            for (int nf = 0; nf < 4; ++nf)
                oacc[mf][nf] = mfma16(pa[mf], vb[nf], oacc[mf][nf]);
    }
    __syncthreads();
#pragma unroll
    for (int mf = 0; mf < 4; ++mf)
#pragma unroll
        for (int nf = 0; nf < 4; ++nf)
#pragma unroll
            for (int j = 0; j < 4; ++j)
                Pl[mf * 16 + lg * 4 + j][nf * 16 + lr] = (f16)oacc[mf][nf][j];
    __syncthreads();
    f16* crow = ctx + (size_t)(bb * 64 + lane) * DMODEL + hh * 64;
#pragma unroll
    for (int i = 0; i < 8; ++i) {
        f16x8 v = *(const f16x8*)&Pl[lane][i * 8];
        *(f16x8*)(crow + i * 8) = v;
    }
}

// ---------------- LayerNorm from fused partials: out = LN(res) (f16) ---------
__global__ __launch_bounds__(128) void ln_k(const f16* __restrict__ res, const float2* __restrict__ part,
                                            const float* __restrict__ g, const float* __restrict__ b,
                                            f16* __restrict__ out) {
    int row = blockIdx.x;
    int t = threadIdx.x;
    f16x8 rv = ((const f16x8*)(res + (size_t)row * DMODEL))[t];
    float s = 0.f, ss = 0.f;
#pragma unroll
    for (int c = 0; c < 8; ++c) {
        float2 p = part[(size_t)row * 8 + c];
        s += p.x; ss += p.y;
    }
    float mean = s * (1.f / 1024.f);
    float var = ss * (1.f / 1024.f) - mean * mean;
    float rstd = rsqrtf(var + 1e-5f);
    float4 g0 = ((const float4*)g)[t * 2], g1 = ((const float4*)g)[t * 2 + 1];
    float4 b0 = ((const float4*)b)[t * 2], b1 = ((const float4*)b)[t * 2 + 1];
    f16x8 o;
    o[0] = (f16)(((float)rv[0] - mean) * rstd * g0.x + b0.x);
    o[1] = (f16)(((float)rv[1] - mean) * rstd * g0.y + b0.y);
    o[2] = (f16)(((float)rv[2] - mean) * rstd * g0.z + b0.z);
    o[3] = (f16)(((float)rv[3] - mean) * rstd * g0.w + b0.w);
    o[4] = (f16)(((float)rv[4] - mean) * rstd * g1.x + b1.x);
    o[5] = (f16)(((float)rv[5] - mean) * rstd * g1.y + b1.y);
    o[6] = (f16)(((float)rv[6] - mean) * rstd * g1.z + b1.z);
    o[7] = (f16)(((float)rv[7] - mean) * rstd * g1.w + b1.w);
    ((f16x8*)(out + (size_t)row * DMODEL))[t] = o;
}

// ---------------- final LayerNorm: f16 in -> fp32 h out (own stats) ----------
__global__ __launch_bounds__(256) void lnf_k(const f16* __restrict__ res, const float* __restrict__ g,
                                             const float* __restrict__ b, float* __restrict__ h) {
    int row = blockIdx.x;
    int t = threadIdx.x;
    f16x4 rv = ((const f16x4*)(res + (size_t)row * DMODEL))[t];
    float v0 = (float)rv[0], v1 = (float)rv[1], v2 = (float)rv[2], v3 = (float)rv[3];
    float s = v0 + v1 + v2 + v3;
    float ss = v0 * v0 + v1 * v1 + v2 * v2 + v3 * v3;
    for (int m = 1; m < 64; m <<= 1) { s += __shfl_xor(s, m); ss += __shfl_xor(ss, m); }
    __shared__ float red[8];
    if ((t & 63) == 0) { red[(t >> 6) * 2] = s; red[(t >> 6) * 2 + 1] = ss; }
    __syncthreads();
    s = red[0] + red[2] + red[4] + red[6];
    ss = red[1] + red[3] + red[5] + red[7];
    float mean = s * (1.f / 1024.f);
    float var = ss * (1.f / 1024.f) - mean * mean;
    float rstd = rsqrtf(var + 1e-5f);
    float4 gg = ((const float4*)g)[t];
    float4 bb = ((const float4*)b)[t];
    float4 o;
    o.x = (v0 - mean) * rstd * gg.x + bb.x;
    o.y = (v1 - mean) * rstd * gg.y + bb.y;
    o.z = (v2 - mean) * rstd * gg.z + bb.z;
    o.w = (v3 - mean) * rstd * gg.w + bb.w;
    ((float4*)(h + (size_t)row * DMODEL))[t] = o;
}

// ---------------- mean over S -------------------------------------------------
__global__ __launch_bounds__(256) void pool_k(const float* __restrict__ h, float* __restrict__ pooled) {
    int b = blockIdx.x;
    int t = threadIdx.x;
    float sx = 0, sy = 0, sz = 0, sw = 0;
    for (int s = 0; s < SEQ; ++s) {
        float4 v = ((const float4*)(h + (size_t)(b * SEQ + s) * DMODEL))[t];
        sx += v.x; sy += v.y; sz += v.z; sw += v.w;
    }
    float4 o; o.x = sx * (1.f / 64.f); o.y = sy * (1.f / 64.f); o.z = sz * (1.f / 64.f); o.w = sw * (1.f / 64.f);
    ((float4*)(pooled + (size_t)b * DMODEL))[t] = o;
}

// ---------------- policy / value heads ---------------------------------------
__global__ __launch_bounds__(64) void head_k(const float* __restrict__ pooled, const float* __restrict__ pw,
                                             const float* __restrict__ pb, const float* __restrict__ vw,
                                             const float* __restrict__ vb, float* __restrict__ out) {
    int b = blockIdx.x;
    int lane = threadIdx.x;
    const float* pr = pooled + (size_t)b * DMODEL;
    const float* wr = pw + (size_t)lane * DMODEL;
    float accp = 0.f;
    for (int d = 0; d < DMODEL; d += 4) {
        float4 x = *(const float4*)(pr + d);
        float4 w = *(const float4*)(wr + d);
        accp += x.x * w.x + x.y * w.y + x.z * w.z + x.w * w.w;
    }
    float accv = 0.f;
    for (int d = lane * 4; d < DMODEL; d += 256) {
        float4 x = *(const float4*)(pr + d);
        float4 w = *(const float4*)(vw + d);
        accv += x.x * w.x + x.y * w.y + x.z * w.z + x.w * w.w;
    }
    for (int m = 1; m < 64; m <<= 1) accv += __shfl_xor(accv, m);
    out[b * VOCAB + lane] = accp + pb[lane];
    if (lane == 0) out[BATCH * VOCAB + b] = accv + vb[0];
}

extern "C" void kernel_launch(void* const* d_in, const int* in_sizes, int n_in,
                              void* d_out, int out_size, void* d_ws, size_t ws_size,
                              hipStream_t stream) {
    const int*   x      = (const int*)d_in[0];
    const int*   step   = (const int*)d_in[1];
    const float* tok    = (const float*)d_in[2];
    const float* se     = (const float*)d_in[3];
    const float* qkv_w  = (const float*)d_in[4];
    const float* qkv_b  = (const float*)d_in[5];
    const float* out_w  = (const float*)d_in[6];
    const float* out_b  = (const float*)d_in[7];
    const float* relb   = (const float*)d_in[8];
    const float* w1     = (const float*)d_in[9];
    const float* b1     = (const float*)d_in[10];
    const float* w2     = (const float*)d_in[11];
    const float* b2     = (const float*)d_in[12];
    const float* ln1g   = (const float*)d_in[13];
    const float* ln1b   = (const float*)d_in[14];
    const float* ln2g   = (const float*)d_in[15];
    const float* ln2b   = (const float*)d_in[16];
    const float* lnog   = (const float*)d_in[17];
    const float* lnob   = (const float*)d_in[18];
    const float* pw     = (const float*)d_in[19];
    const float* pb     = (const float*)d_in[20];
    const float* vw     = (const float*)d_in[21];
    const float* vb     = (const float*)d_in[22];

    float* out = (float*)d_out;
    float* h = out + BATCH * VOCAB + BATCH;       // final fp32 h output [16384,1024]

    char* ws = (char*)d_ws;
    f16* rB     = (f16*)(ws);                       // residual (live)      32 MB
    f16* resA   = (f16*)(ws + 33554432);            // residual+delta       32 MB
    f16* qkv16  = (f16*)(ws + 67108864);            // 96 MB
    f16* ctx16  = (f16*)(ws + 167772160);           // 32 MB
    f16* ffn16  = (f16*)(ws + 67108864);            // 128 MB (union with qkv+ctx)
    f16* wqb    = (f16*)(ws + 201326592);
    f16* wob    = (f16*)(ws + 207618048);
    f16* w1b    = (f16*)(ws + 209715200);
    f16* w2b    = (f16*)(ws + 218103808);
    float2* part = (float2*)(ws + 226492416);       // [16384][8] = 1 MB
    float* pooled = (float*)(ws + 226492416);       // reuses part (disjoint lifetime)

    embed_k<<<MS, 256, 0, stream>>>(x, step, tok, se, rB);

    for (int l = 0; l < NLAYER; ++l) {
        cvt4_k<<<12288, 256, 0, stream>>>(qkv_w + (size_t)l * 3145728, out_w + (size_t)l * 1048576,
                                          w1 + (size_t)l * 4194304, w2 + (size_t)l * 4194304,
                                          wqb, wob, w1b, w2b);

        gemm_k<0><<<dim3(24, 64), 256, 0, stream>>>(rB, wqb, qkv_b + l * 3072, qkv16,
                                                    nullptr, nullptr, nullptr, MS, 3072, 1024);
        attn_k<<<dim3(NHEAD, BATCH), 64, 0, stream>>>(qkv16, relb + l * 127, ctx16);
        gemm_k<2><<<dim3(8, 64), 256, 0, stream>>>(ctx16, wob, out_b + l * 1024, nullptr,
                                                   rB, resA, part, MS, 1024, 1024);
        ln_k<<<MS, 128, 0, stream>>>(resA, part, ln1g + l * 1024, ln1b + l * 1024, rB);
        gemm_k<1><<<dim3(32, 64), 256, 0, stream>>>(rB, w1b, b1 + l * 4096, ffn16,
                                                    nullptr, nullptr, nullptr, MS, 4096, 1024);
        gemm_k<2><<<dim3(8, 64), 256, 0, stream>>>(ffn16, w2b, b2 + l * 1024, nullptr,
                                                   rB, resA, part, MS, 1024, 4096);
        ln_k<<<MS, 128, 0, stream>>>(resA, part, ln2g + l * 1024, ln2b + l * 1024, rB);
    }

    lnf_k<<<MS, 256, 0, stream>>>(rB, lnog, lnob, h);
    pool_k<<<BATCH, 256, 0, stream>>>(h, pooled);
    head_k<<<BATCH, 64, 0, stream>>>(pooled, pw, pb, vw, vb, out);
}

// Round 10
// 4660.220 us; speedup vs baseline: 1.3429x; 1.0428x over previous
//
#include <hip/hip_runtime.h>
#include <math.h>

typedef _Float16 f16;
typedef _Float16 f16x8 __attribute__((ext_vector_type(8)));
typedef _Float16 f16x4 __attribute__((ext_vector_type(4)));
typedef float floatx4 __attribute__((ext_vector_type(4)));

#define BATCH 256
#define SEQ 64
#define DMODEL 1024
#define NHEAD 16
#define HDIM 64
#define VOCAB 64
#define DFF 4096
#define NLAYER 8
#define MS (BATCH*SEQ)   // 16384 rows

#define GPTR(p) ((const __attribute__((address_space(1))) void*)(p))
#define LPTR(p) ((__attribute__((address_space(3))) void*)(p))
#define GLDS(s, d) __builtin_amdgcn_global_load_lds(GPTR(s), LPTR(d), 16, 0, 0)
#define BARR() asm volatile("s_barrier" ::: "memory")

__device__ __forceinline__ floatx4 mfma16(f16x8 a, f16x8 b, floatx4 c) {
    return __builtin_amdgcn_mfma_f32_16x16x32_f16(a, b, c, 0, 0, 0);
}

// fast gelu: x * sigmoid(1.5957691216 * (x + 0.044715 x^3)); max |err| ~3e-4
__device__ __forceinline__ float gelu_f(float x) {
    float x3 = x * x * x;
    float y = -1.5957691216f * fmaf(0.044715f, x3, x);
    return x / (1.f + __expf(y));
}

// ---------------- embed ------------------------------------------------------
__global__ __launch_bounds__(256) void embed_k(const int* __restrict__ x, const int* __restrict__ step,
                                               const float* __restrict__ tok, const float* __restrict__ se,
                                               f16* __restrict__ r) {
    int row = blockIdx.x;
    int t = threadIdx.x;
    int id = x[row];
    int si = min(max(step[0], 0), 63);
    float4 a = ((const float4*)(tok + (size_t)id * DMODEL))[t];
    float4 b = ((const float4*)(se + (size_t)si * DMODEL))[t];
    f16x4 hv; hv[0] = (f16)(a.x + b.x); hv[1] = (f16)(a.y + b.y);
    hv[2] = (f16)(a.z + b.z); hv[3] = (f16)(a.w + b.w);
    ((f16x4*)(r + (size_t)row * DMODEL))[t] = hv;
}

// ---------------- fp32 -> f16 convert, all 4 weight mats of a layer ----------
__global__ __launch_bounds__(256) void cvt4_k(const float* __restrict__ qw, const float* __restrict__ ow,
                                              const float* __restrict__ w1, const float* __restrict__ w2,
                                              f16* __restrict__ dq, f16* __restrict__ dO,
                                              f16* __restrict__ d1, f16* __restrict__ d2) {
    int gid = blockIdx.x * 256 + threadIdx.x;
    const float4* s; f16x4* d; int off;
    if (gid < 786432)        { s = (const float4*)qw; d = (f16x4*)dq; off = gid; }
    else if (gid < 1048576)  { s = (const float4*)ow; d = (f16x4*)dO; off = gid - 786432; }
    else if (gid < 2097152)  { s = (const float4*)w1; d = (f16x4*)d1; off = gid - 1048576; }
    else                     { s = (const float4*)w2; d = (f16x4*)d2; off = gid - 2097152; }
    float4 v = s[off];
    f16x4 o; o[0] = (f16)v.x; o[1] = (f16)v.y; o[2] = (f16)v.z; o[3] = (f16)v.w;
    d[off] = o;
}

// ========== 8-phase GEMM (256x256 tile, BK=64, dbuf, counted vmcnt) ==========
// 8 waves (2M x 4N), per-wave 128x64 (acc[8][4]). Per K-tile: 4 phases of
// {ds_reads(12 or 4), 1 stage, barrier, lgkm0+schedbar, prio1 16MFMA prio0, barrier}.
// Stage slots (strictly race-free): p0: A(t+1)->other buf (that buf fully consumed
// last tile); p1/p2: B(t+2) halves -> current buf (B consumed at p0's end-barrier).
// Boundary: vmcnt(4) folded into p3's end-barrier (leaves B(t+2) in flight).
// T2 swizzle: phys 16B-block p at row r holds logical p^(r&7); pre-swizzled source.
// MODE 0: store f16 (bias)   MODE 1: store f16 (bias+gelu)
template<int MODE>
__global__ __launch_bounds__(512, 2) void gemm8_k(const f16* __restrict__ A, const f16* __restrict__ Bw,
                                                  const float* __restrict__ bias, f16* __restrict__ Cb,
                                                  int M, int N, int K) {
    __shared__ f16 smem[65536];   // 2 bufs x (A[256][64] | B[256][64]) = 128 KB

    const int tid = threadIdx.x;
    const int lane = tid & 63;
    const int wave = tid >> 6;               // 0..7
    const int wm = wave >> 2, wn = wave & 3; // 2M x 4N
    const int lr = lane & 15, lg = lane >> 4;
    const int sa = lr & 7;

    // bijective XCD swizzle (all grids have nwg % 8 == 0)
    const unsigned nx = gridDim.x;
    const unsigned nwg = nx * gridDim.y;
    unsigned flat = blockIdx.y * nx + blockIdx.x;
    flat = (flat & 7u) * (nwg >> 3) + (flat >> 3);
    const int m0 = (int)(flat / nx) * 256;
    const int n0 = (int)(flat % nx) * 256;

    floatx4 acc[8][4] = {};

    // staging: thread covers rows srow,+64,+128,+192; 16B-block tid&7, pre-swizzled.
    const int srow = tid >> 3;               // 0..63
    const int scb = (tid & 7) ^ (srow & 7);
    const f16* Ag = A + (size_t)(m0 + srow) * K + scb * 8;
    const f16* Bg = Bw + (size_t)(n0 + srow) * K + scb * 8;
    const int ldsw = wave * 512;             // wave-uniform; HW adds lane*16B

#define STAGE_A(bi, tt) do { const f16* _p = Ag + (size_t)(tt) * 64;                       \
    f16* _d = smem + (bi) * 32768 + ldsw;                                                  \
    GLDS(_p, _d); GLDS(_p + 64 * (size_t)K, _d + 4096);                                    \
    GLDS(_p + 128 * (size_t)K, _d + 8192); GLDS(_p + 192 * (size_t)K, _d + 12288); } while (0)
#define STAGE_BH(bi, tt, h) do { const f16* _p = Bg + (size_t)(tt) * 64 + (size_t)(h) * 128 * K; \
    f16* _d = smem + (bi) * 32768 + 16384 + (h) * 8192 + ldsw;                             \
    GLDS(_p, _d); GLDS(_p + 64 * (size_t)K, _d + 4096); } while (0)

    const int NT = K >> 6;   // K=1024 -> 16

    // prologue: A(0)+B(0) -> buf0, B(1) -> buf1; wait all but B(1)'s 4 loads.
    STAGE_A(0, 0);
    STAGE_BH(0, 0, 0); STAGE_BH(0, 0, 1);
    STAGE_BH(1, 1, 0); STAGE_BH(1, 1, 1);
    asm volatile("s_waitcnt vmcnt(4)" ::: "memory");
    BARR();

    for (int t = 0; t < NT; ++t) {
        const int pofs = (t & 1) << 15;
        const f16* Ab = smem + pofs;
        const f16* Bb = smem + pofs + 16384;
        f16x8 bf[4][2];

        // ---- phase 0: B all (8 reads) + A q0 (4 reads); stage A(t+1) ----
        {
            f16x8 af[2][2];
#pragma unroll
            for (int kh = 0; kh < 2; ++kh)
#pragma unroll
                for (int i = 0; i < 2; ++i)
                    af[i][kh] = *(const f16x8*)(Ab + (wm * 128 + i * 16 + lr) * 64 + (((kh * 4 + lg) ^ sa) << 3));
#pragma unroll
            for (int kh = 0; kh < 2; ++kh)
#pragma unroll
                for (int ni = 0; ni < 4; ++ni)
                    bf[ni][kh] = *(const f16x8*)(Bb + (wn * 64 + ni * 16 + lr) * 64 + (((kh * 4 + lg) ^ sa) << 3));
            if (t + 1 < NT) STAGE_A((t & 1) ^ 1, t + 1);
            asm volatile("s_waitcnt lgkmcnt(8)" ::: "memory");
            BARR();
            asm volatile("s_waitcnt lgkmcnt(0)" ::: "memory");
            __builtin_amdgcn_sched_barrier(0);
            __builtin_amdgcn_s_setprio(1);
#pragma unroll
            for (int kh = 0; kh < 2; ++kh)
#pragma unroll
                for (int i = 0; i < 2; ++i)
#pragma unroll
                    for (int ni = 0; ni < 4; ++ni)
                        acc[i][ni] = mfma16(af[i][kh], bf[ni][kh], acc[i][ni]);
            __builtin_amdgcn_s_setprio(0);
            BARR();
        }
        // ---- phases 1..3: A quadrant q (4 reads); stage B(t+2) halves ----
#pragma unroll
        for (int q = 1; q < 4; ++q) {
            f16x8 af[2][2];
#pragma unroll
            for (int kh = 0; kh < 2; ++kh)
#pragma unroll
                for (int i = 0; i < 2; ++i)
                    af[i][kh] = *(const f16x8*)(Ab + (wm * 128 + q * 32 + i * 16 + lr) * 64 + (((kh * 4 + lg) ^ sa) << 3));
            if (q == 1 && t + 2 < NT) STAGE_BH(t & 1, t + 2, 0);
            if (q == 2 && t + 2 < NT) STAGE_BH(t & 1, t + 2, 1);
            BARR();
            asm volatile("s_waitcnt lgkmcnt(0)" ::: "memory");
            __builtin_amdgcn_sched_barrier(0);
            __builtin_amdgcn_s_setprio(1);
#pragma unroll
            for (int kh = 0; kh < 2; ++kh)
#pragma unroll
                for (int i = 0; i < 2; ++i)
#pragma unroll
                    for (int ni = 0; ni < 4; ++ni)
                        acc[q * 2 + i][ni] = mfma16(af[i][kh], bf[ni][kh], acc[q * 2 + i][ni]);
            __builtin_amdgcn_s_setprio(0);
            // boundary wait folded into p3's end-barrier:
            if (q == 3) {
                if (t + 2 < NT)      { asm volatile("s_waitcnt vmcnt(4)" ::: "memory"); }
                else if (t + 1 < NT) { asm volatile("s_waitcnt vmcnt(0)" ::: "memory"); }
            }
            BARR();
        }
    }
#undef STAGE_A
#undef STAGE_BH

    // epilogue: wave-private 128x64 f16 scratch (LDS free, all waves synced)
    f16* scr = smem + wave * 8192;
    float bsv[4];
#pragma unroll
    for (int ni = 0; ni < 4; ++ni) bsv[ni] = bias[n0 + wn * 64 + ni * 16 + lr];
#pragma unroll
    for (int mi = 0; mi < 8; ++mi)
#pragma unroll
        for (int ni = 0; ni < 4; ++ni)
#pragma unroll
            for (int j = 0; j < 4; ++j) {
                int rr = mi * 16 + lg * 4 + j;
                int cc = ni * 16 + lr;
                float v = acc[mi][ni][j] + bsv[ni];
                if (MODE == 1) v = gelu_f(v);
                scr[rr * 64 + (((cc >> 3) ^ (rr & 7)) * 8) + (cc & 7)] = (f16)v;
            }
#pragma unroll
    for (int half = 0; half < 2; ++half) {
        int r2 = half * 64 + lane;
        int gr = m0 + wm * 128 + r2;
        f16* dst = Cb + (size_t)gr * N + n0 + wn * 64;
#pragma unroll
        for (int i = 0; i < 8; ++i) {
            f16x8 v = *(const f16x8*)(scr + r2 * 64 + ((i ^ (r2 & 7)) * 8));
            *(f16x8*)(dst + i * 8) = v;
        }
    }
}

// ========== r8 GEMM (128x128, BK=64, A2+B3 ring, vmcnt(4)) — MODE 2 ==========
// res = Rres + acc + bias -> f16 ResOut + per-row partial (sum,sumsq)
__global__ __launch_bounds__(256, 2) void gemm2_k(const f16* __restrict__ A, const f16* __restrict__ Bw,
                                                  const float* __restrict__ bias,
                                                  const f16* __restrict__ Rres, f16* __restrict__ ResOut,
                                                  float2* __restrict__ Part,
                                                  int M, int N, int K) {
    __shared__ f16 smem[40960];   // A: [2][8192] at 0 ; B: [3][8192] at 16384

    const int tid = threadIdx.x;
    const int lane = tid & 63;
    const int wave = tid >> 6;
    const int wm = wave >> 1, wn = wave & 1;
    const int lr = lane & 15, lg = lane >> 4;
    const int sa = lr & 7;

    const unsigned nx = gridDim.x;
    const unsigned nwg = nx * gridDim.y;
    unsigned flat = blockIdx.y * nx + blockIdx.x;
    flat = (flat & 7u) * (nwg >> 3) + (flat >> 3);
    const int m0 = (int)(flat / nx) * 128;
    const int n0 = (int)(flat % nx) * 128;

    floatx4 acc[4][4] = {};

    const int srow = tid >> 3;
    const int scbs = (tid & 7) ^ (srow & 7);
    const f16* Asrc = A + (size_t)(m0 + srow) * K + scbs * 8;
    const f16* Bsrc = Bw + (size_t)(n0 + srow) * K + scbs * 8;
    const int ldsw = wave * 512;

#define STAGEA(bi, tt) do { const f16* _a = Asrc + (size_t)(tt) * 64;                      \
    f16* _l = smem + (bi) * 8192 + ldsw;                                                   \
    GLDS(_a, _l); GLDS(_a + 32 * (size_t)K, _l + 2048);                                    \
    GLDS(_a + 64 * (size_t)K, _l + 4096); GLDS(_a + 96 * (size_t)K, _l + 6144); } while (0)
#define STAGEB(bi, tt) do { const f16* _b = Bsrc + (size_t)(tt) * 64;                      \
    f16* _l = smem + 16384 + (bi) * 8192 + ldsw;                                           \
    GLDS(_b, _l); GLDS(_b + 32 * (size_t)K, _l + 2048);                                    \
    GLDS(_b + 64 * (size_t)K, _l + 4096); GLDS(_b + 96 * (size_t)K, _l + 6144); } while (0)

    const int NT = K >> 6;

    STAGEA(0, 0);
    STAGEB(0, 0);
    STAGEB(1, 1);
    asm volatile("s_waitcnt vmcnt(4)" ::: "memory");
    __builtin_amdgcn_s_barrier();

    int ab = 0, bb = 0;
    for (int t = 0; t < NT; ++t) {
        if (t + 1 < NT) STAGEA(ab ^ 1, t + 1);
        if (t + 2 < NT) { int b2 = bb + 2; if (b2 >= 3) b2 -= 3; STAGEB(b2, t + 2); }

        const f16* Ab = smem + ab * 8192;
        const f16* Bb = smem + 16384 + bb * 8192;
        f16x8 af[8], bf[8];
#pragma unroll
        for (int kh = 0; kh < 2; ++kh)
#pragma unroll
            for (int mi = 0; mi < 4; ++mi)
                af[kh * 4 + mi] = *(const f16x8*)(Ab + (wm * 64 + mi * 16 + lr) * 64
                                                  + (((kh * 4 + lg) ^ sa) << 3));
#pragma unroll
        for (int kh = 0; kh < 2; ++kh)
#pragma unroll
            for (int ni = 0; ni < 4; ++ni)
                bf[kh * 4 + ni] = *(const f16x8*)(Bb + (wn * 64 + ni * 16 + lr) * 64
                                                  + (((kh * 4 + lg) ^ sa) << 3));

        __builtin_amdgcn_s_setprio(1);
#pragma unroll
        for (int kh = 0; kh < 2; ++kh)
#pragma unroll
            for (int mi = 0; mi < 4; ++mi)
#pragma unroll
                for (int ni = 0; ni < 4; ++ni)
                    acc[mi][ni] = mfma16(af[kh * 4 + mi], bf[kh * 4 + ni], acc[mi][ni]);
        __builtin_amdgcn_s_setprio(0);

        if (t + 2 < NT)      { asm volatile("s_waitcnt vmcnt(4)" ::: "memory"); }
        else if (t + 1 < NT) { asm volatile("s_waitcnt vmcnt(0)" ::: "memory"); }
        __builtin_amdgcn_s_barrier();

        ab ^= 1;
        bb = (bb == 2) ? 0 : bb + 1;
    }
#undef STAGEA
#undef STAGEB

    float bsv[4];
#pragma unroll
    for (int ni = 0; ni < 4; ++ni) bsv[ni] = bias[n0 + wn * 64 + ni * 16 + lr];
    f16* scr = smem + wave * 4096;
#pragma unroll
    for (int mi = 0; mi < 4; ++mi)
#pragma unroll
        for (int ni = 0; ni < 4; ++ni)
#pragma unroll
            for (int j = 0; j < 4; ++j) {
                int rr = mi * 16 + lg * 4 + j;
                int cc = ni * 16 + lr;
                scr[rr * 64 + (((cc >> 3) ^ (rr & 7)) * 8) + (cc & 7)]
                    = (f16)(acc[mi][ni][j] + bsv[ni]);
            }
    int gr = m0 + wm * 64 + lane;
    const f16* rrow = Rres + (size_t)gr * N + n0 + wn * 64;
    f16* orow = ResOut + (size_t)gr * N + n0 + wn * 64;
    float s = 0.f, ss = 0.f;
#pragma unroll
    for (int i = 0; i < 8; ++i) {
        f16x8 a = *(const f16x8*)(scr + lane * 64 + ((i ^ (lane & 7)) * 8));
        f16x8 rv = *(const f16x8*)(rrow + i * 8);
        f16x8 o;
#pragma unroll
        for (int k = 0; k < 8; ++k) {
            float v = (float)a[k] + (float)rv[k];
            s += v; ss += v * v;
            o[k] = (f16)v;
        }
        *(f16x8*)(orow + i * 8) = o;
    }
    float* red = (float*)(smem + 16384);
    if (wn == 1) { red[(wm * 64 + lane) * 2] = s; red[(wm * 64 + lane) * 2 + 1] = ss; }
    __syncthreads();
    if (wn == 0) {
        float s2 = red[(wm * 64 + lane) * 2], ss2 = red[(wm * 64 + lane) * 2 + 1];
        Part[(size_t)gr * (N >> 7) + (n0 >> 7)] = float2{s + s2, ss + ss2};
    }
}

// ---------------- attention: one wave per (b,h) -------------------------------
__global__ __launch_bounds__(64) void attn_k(const f16* __restrict__ qkv, const float* __restrict__ rb,
                                             f16* __restrict__ ctx) {
    const int hh = blockIdx.x;
    const int bb = blockIdx.y;
    const int lane = threadIdx.x;
    __shared__ float rbs[128];
    __shared__ f16 Vt[64][72];
    __shared__ f16 Pl[64][72];

    for (int i = lane; i < 127; i += 64) rbs[i] = rb[i];

    const f16* vrow = qkv + (size_t)(bb * 64 + lane) * 3072 + 2048 + hh * 64;
#pragma unroll
    for (int i = 0; i < 8; ++i) {
        f16x8 v = *(const f16x8*)(vrow + i * 8);
#pragma unroll
        for (int j = 0; j < 8; ++j) Vt[i * 8 + j][lane] = v[j];
    }
    __syncthreads();

    const int lr = lane & 15, lg = lane >> 4;
    floatx4 sacc[4][4] = {};
    const f16* qbase = qkv + (size_t)(bb * 64) * 3072 + hh * 64;
#pragma unroll
    for (int kk = 0; kk < 64; kk += 32) {
        f16x8 qa[4], kb[4];
#pragma unroll
        for (int mf = 0; mf < 4; ++mf)
            qa[mf] = *(const f16x8*)(qbase + (size_t)(mf * 16 + lr) * 3072 + kk + lg * 8);
#pragma unroll
        for (int nf = 0; nf < 4; ++nf)
            kb[nf] = *(const f16x8*)(qbase + 1024 + (size_t)(nf * 16 + lr) * 3072 + kk + lg * 8);
#pragma unroll
        for (int mf = 0; mf < 4; ++mf)
#pragma unroll
            for (int nf = 0; nf < 4; ++nf)
                sacc[mf][nf] = mfma16(qa[mf], kb[nf], sacc[mf][nf]);
    }

#pragma unroll
    for (int mf = 0; mf < 4; ++mf) {
#pragma unroll
        for (int j = 0; j < 4; ++j) {
            int qrow = mf * 16 + lg * 4 + j;
            float v0 = sacc[mf][0][j] * 0.125f + rbs[qrow - (0  + lr) + 63];
            float v1 = sacc[mf][1][j] * 0.125f + rbs[qrow - (16 + lr) + 63];
            float v2 = sacc[mf][2][j] * 0.125f + rbs[qrow - (32 + lr) + 63];
            float v3 = sacc[mf][3][j] * 0.125f + rbs[qrow - (48 + lr) + 63];
            float mx = fmaxf(fmaxf(v0, v1), fmaxf(v2, v3));
            for (int m = 1; m < 16; m <<= 1) mx = fmaxf(mx, __shfl_xor(mx, m));
            v0 = __expf(v0 - mx); v1 = __expf(v1 - mx); v2 = __expf(v2 - mx); v3 = __expf(v3 - mx);
            float sum = v0 + v1 + v2 + v3;
            for (int m = 1; m < 16; m <<= 1) sum += __shfl_xor(sum, m);
            float inv = 1.f / sum;
            Pl[qrow][0  + lr] = (f16)(v0 * inv);
            Pl[qrow][16 + lr] = (f16)(v1 * inv);
            Pl[qrow][32 + lr] = (f16)(v2 * inv);
            Pl[qrow][48 + lr] = (f16)(v3 * inv);
        }
    }
    __syncthreads();

    floatx4 oacc[4][4] = {};
#pragma unroll
    for (int kk = 0; kk < 64; kk += 32) {
        f16x8 pa[4], vb[4];
#pragma unroll
        for (int mf = 0; mf < 4; ++mf) pa[mf] = *(const f16x8*)&Pl[mf * 16 + lr][kk + lg * 8];
#pragma unroll
        for (int nf = 0; nf < 4; ++nf) vb[nf] = *(const f16x8*)&Vt[nf * 16 + lr][kk + lg * 8];
#pragma unroll
        for (int mf = 0; mf < 4; ++mf)
#pragma unroll
            for (int nf = 0; nf < 4; ++nf)
                oacc[mf][nf] = mfma16(pa[mf], vb[nf], oacc[mf][nf]);
    }
    __syncthreads();
#pragma unroll
    for (int mf = 0; mf < 4; ++mf)
#pragma unroll
        for (int nf = 0; nf < 4; ++nf)
#pragma unroll
            for (int j = 0; j < 4; ++j)
                Pl[mf * 16 + lg * 4 + j][nf * 16 + lr] = (f16)oacc[mf][nf][j];
    __syncthreads();
    f16* crow = ctx + (size_t)(bb * 64 + lane) * DMODEL + hh * 64;
#pragma unroll
    for (int i = 0; i < 8; ++i) {
        f16x8 v = *(const f16x8*)&Pl[lane][i * 8];
        *(f16x8*)(crow + i * 8) = v;
    }
}

// ---------------- LayerNorm from fused partials: out = LN(res) (f16) ---------
__global__ __launch_bounds__(128) void ln_k(const f16* __restrict__ res, const float2* __restrict__ part,
                                            const float* __restrict__ g, const float* __restrict__ b,
                                            f16* __restrict__ out) {
    int row = blockIdx.x;
    int t = threadIdx.x;
    f16x8 rv = ((const f16x8*)(res + (size_t)row * DMODEL))[t];
    float s = 0.f, ss = 0.f;
#pragma unroll
    for (int c = 0; c < 8; ++c) {
        float2 p = part[(size_t)row * 8 + c];
        s += p.x; ss += p.y;
    }
    float mean = s * (1.f / 1024.f);
    float var = ss * (1.f / 1024.f) - mean * mean;
    float rstd = rsqrtf(var + 1e-5f);
    float4 g0 = ((const float4*)g)[t * 2], g1 = ((const float4*)g)[t * 2 + 1];
    float4 b0 = ((const float4*)b)[t * 2], b1 = ((const float4*)b)[t * 2 + 1];
    f16x8 o;
    o[0] = (f16)(((float)rv[0] - mean) * rstd * g0.x + b0.x);
    o[1] = (f16)(((float)rv[1] - mean) * rstd * g0.y + b0.y);
    o[2] = (f16)(((float)rv[2] - mean) * rstd * g0.z + b0.z);
    o[3] = (f16)(((float)rv[3] - mean) * rstd * g0.w + b0.w);
    o[4] = (f16)(((float)rv[4] - mean) * rstd * g1.x + b1.x);
    o[5] = (f16)(((float)rv[5] - mean) * rstd * g1.y + b1.y);
    o[6] = (f16)(((float)rv[6] - mean) * rstd * g1.z + b1.z);
    o[7] = (f16)(((float)rv[7] - mean) * rstd * g1.w + b1.w);
    ((f16x8*)(out + (size_t)row * DMODEL))[t] = o;
}

// ---------------- final LayerNorm: f16 in -> fp32 h out (own stats) ----------
__global__ __launch_bounds__(256) void lnf_k(const f16* __restrict__ res, const float* __restrict__ g,
                                             const float* __restrict__ b, float* __restrict__ h) {
    int row = blockIdx.x;
    int t = threadIdx.x;
    f16x4 rv = ((const f16x4*)(res + (size_t)row * DMODEL))[t];
    float v0 = (float)rv[0], v1 = (float)rv[1], v2 = (float)rv[2], v3 = (float)rv[3];
    float s = v0 + v1 + v2 + v3;
    float ss = v0 * v0 + v1 * v1 + v2 * v2 + v3 * v3;
    for (int m = 1; m < 64; m <<= 1) { s += __shfl_xor(s, m); ss += __shfl_xor(ss, m); }
    __shared__ float red[8];
    if ((t & 63) == 0) { red[(t >> 6) * 2] = s; red[(t >> 6) * 2 + 1] = ss; }
    __syncthreads();
    s = red[0] + red[2] + red[4] + red[6];
    ss = red[1] + red[3] + red[5] + red[7];
    float mean = s * (1.f / 1024.f);
    float var = ss * (1.f / 1024.f) - mean * mean;
    float rstd = rsqrtf(var + 1e-5f);
    float4 gg = ((const float4*)g)[t];
    float4 bb = ((const float4*)b)[t];
    float4 o;
    o.x = (v0 - mean) * rstd * gg.x + bb.x;
    o.y = (v1 - mean) * rstd * gg.y + bb.y;
    o.z = (v2 - mean) * rstd * gg.z + bb.z;
    o.w = (v3 - mean) * rstd * gg.w + bb.w;
    ((float4*)(h + (size_t)row * DMODEL))[t] = o;
}

// ---------------- mean over S -------------------------------------------------
__global__ __launch_bounds__(256) void pool_k(const float* __restrict__ h, float* __restrict__ pooled) {
    int b = blockIdx.x;
    int t = threadIdx.x;
    float sx = 0, sy = 0, sz = 0, sw = 0;
    for (int s = 0; s < SEQ; ++s) {
        float4 v = ((const float4*)(h + (size_t)(b * SEQ + s) * DMODEL))[t];
        sx += v.x; sy += v.y; sz += v.z; sw += v.w;
    }
    float4 o; o.x = sx * (1.f / 64.f); o.y = sy * (1.f / 64.f); o.z = sz * (1.f / 64.f); o.w = sw * (1.f / 64.f);
    ((float4*)(pooled + (size_t)b * DMODEL))[t] = o;
}

// ---------------- policy / value heads ---------------------------------------
__global__ __launch_bounds__(64) void head_k(const float* __restrict__ pooled, const float* __restrict__ pw,
                                             const float* __restrict__ pb, const float* __restrict__ vw,
                                             const float* __restrict__ vb, float* __restrict__ out) {
    int b = blockIdx.x;
    int lane = threadIdx.x;
    const float* pr = pooled + (size_t)b * DMODEL;
    const float* wr = pw + (size_t)lane * DMODEL;
    float accp = 0.f;
    for (int d = 0; d < DMODEL; d += 4) {
        float4 x = *(const float4*)(pr + d);
        float4 w = *(const float4*)(wr + d);
        accp += x.x * w.x + x.y * w.y + x.z * w.z + x.w * w.w;
    }
    float accv = 0.f;
    for (int d = lane * 4; d < DMODEL; d += 256) {
        float4 x = *(const float4*)(pr + d);
        float4 w = *(const float4*)(vw + d);
        accv += x.x * w.x + x.y * w.y + x.z * w.z + x.w * w.w;
    }
    for (int m = 1; m < 64; m <<= 1) accv += __shfl_xor(accv, m);
    out[b * VOCAB + lane] = accp + pb[lane];
    if (lane == 0) out[BATCH * VOCAB + b] = accv + vb[0];
}

extern "C" void kernel_launch(void* const* d_in, const int* in_sizes, int n_in,
                              void* d_out, int out_size, void* d_ws, size_t ws_size,
                              hipStream_t stream) {
    const int*   x      = (const int*)d_in[0];
    const int*   step   = (const int*)d_in[1];
    const float* tok    = (const float*)d_in[2];
    const float* se     = (const float*)d_in[3];
    const float* qkv_w  = (const float*)d_in[4];
    const float* qkv_b  = (const float*)d_in[5];
    const float* out_w  = (const float*)d_in[6];
    const float* out_b  = (const float*)d_in[7];
    const float* relb   = (const float*)d_in[8];
    const float* w1     = (const float*)d_in[9];
    const float* b1     = (const float*)d_in[10];
    const float* w2     = (const float*)d_in[11];
    const float* b2     = (const float*)d_in[12];
    const float* ln1g   = (const float*)d_in[13];
    const float* ln1b   = (const float*)d_in[14];
    const float* ln2g   = (const float*)d_in[15];
    const float* ln2b   = (const float*)d_in[16];
    const float* lnog   = (const float*)d_in[17];
    const float* lnob   = (const float*)d_in[18];
    const float* pw     = (const float*)d_in[19];
    const float* pb     = (const float*)d_in[20];
    const float* vw     = (const float*)d_in[21];
    const float* vb     = (const float*)d_in[22];

    float* out = (float*)d_out;
    float* h = out + BATCH * VOCAB + BATCH;       // final fp32 h output [16384,1024]

    char* ws = (char*)d_ws;
    f16* rB     = (f16*)(ws);                       // residual (live)      32 MB
    f16* resA   = (f16*)(ws + 33554432);            // residual+delta       32 MB
    f16* qkv16  = (f16*)(ws + 67108864);            // 96 MB
    f16* ctx16  = (f16*)(ws + 167772160);           // 32 MB
    f16* ffn16  = (f16*)(ws + 67108864);            // 128 MB (union with qkv+ctx)
    f16* wqb    = (f16*)(ws + 201326592);
    f16* wob    = (f16*)(ws + 207618048);
    f16* w1b    = (f16*)(ws + 209715200);
    f16* w2b    = (f16*)(ws + 218103808);
    float2* part = (float2*)(ws + 226492416);       // [16384][8] = 1 MB
    float* pooled = (float*)(ws + 226492416);       // reuses part (disjoint lifetime)

    embed_k<<<MS, 256, 0, stream>>>(x, step, tok, se, rB);

    for (int l = 0; l < NLAYER; ++l) {
        cvt4_k<<<12288, 256, 0, stream>>>(qkv_w + (size_t)l * 3145728, out_w + (size_t)l * 1048576,
                                          w1 + (size_t)l * 4194304, w2 + (size_t)l * 4194304,
                                          wqb, wob, w1b, w2b);

        gemm8_k<0><<<dim3(12, 64), 512, 0, stream>>>(rB, wqb, qkv_b + l * 3072, qkv16, MS, 3072, 1024);
        attn_k<<<dim3(NHEAD, BATCH), 64, 0, stream>>>(qkv16, relb + l * 127, ctx16);
        gemm2_k<<<dim3(8, 128), 256, 0, stream>>>(ctx16, wob, out_b + l * 1024,
                                                  rB, resA, part, MS, 1024, 1024);
        ln_k<<<MS, 128, 0, stream>>>(resA, part, ln1g + l * 1024, ln1b + l * 1024, rB);
        gemm8_k<1><<<dim3(16, 64), 512, 0, stream>>>(rB, w1b, b1 + l * 4096, ffn16, MS, 4096, 1024);
        gemm2_k<<<dim3(8, 128), 256, 0, stream>>>(ffn16, w2b, b2 + l * 1024,
                                                  rB, resA, part, MS, 1024, 4096);
        ln_k<<<MS, 128, 0, stream>>>(resA, part, ln2g + l * 1024, ln2b + l * 1024, rB);
    }

    lnf_k<<<MS, 256, 0, stream>>>(rB, lnog, lnob, h);
    pool_k<<<BATCH, 256, 0, stream>>>(h, pooled);
    head_k<<<BATCH, 64, 0, stream>>>(pooled, pw, pb, vw, vb, out);
}